// Round 13
// baseline (483.350 us; speedup 1.0000x reference)
//
#include <hip/hip_runtime.h>

typedef short bf16x8 __attribute__((ext_vector_type(8)));
typedef float f32x4 __attribute__((ext_vector_type(4)));
typedef float f32x16 __attribute__((ext_vector_type(16)));
using u16 = unsigned short;
using u32 = unsigned int;

#define MFMA_BF16(A, B, C) __builtin_amdgcn_mfma_f32_16x16x32_bf16((A), (B), (C), 0, 0, 0)
#define MFMA32_BF16(A, B, C) __builtin_amdgcn_mfma_f32_32x32x16_bf16((A), (B), (C), 0, 0, 0)

#define CC 256
#define DD 256
#define KK 8192
#define NN 16384     // B*H*W
#define HW 1024      // H*W
#define OUT0 4194304 // B*D*H*W
#define KSPLIT 16
#define KROWS 32     // k-rows (codes) per LDS tile (verified best)
#define CH 516       // u16 stride per 2-row chunk (1032 B; +8 B pad de-banks rows)

static __device__ __forceinline__ float b2f(u16 u) {
    union { u32 i; float f; } v; v.i = ((u32)u) << 16; return v.f;
}
static __device__ __forceinline__ u16 f2b(float f) {  // RNE fp32 -> bf16
    union { float f; u32 i; } v; v.f = f;
    u32 x = v.i;
    u32 r = (x + 0x7fffu + ((x >> 16) & 1u)) >> 16;
    return (u16)r;
}
static __device__ __forceinline__ u32 f2u(float f) {
    union { float f; u32 u; } v; v.f = f; return v.u;
}
static __device__ __forceinline__ void split3(float v, u16& h, u16& m, u16& l) {
    h = f2b(v); float r1 = v - b2f(h);
    m = f2b(r1); float r2 = r1 - b2f(m);
    l = f2b(r2);
}

typedef __attribute__((address_space(1))) const u32 GlbU32;
typedef __attribute__((address_space(3))) u32 LdsU32;
static __device__ __forceinline__ void async_load16(const void* g, void* l) {
    __builtin_amdgcn_global_load_lds((GlbU32*)g, (LdsU32*)l, 16, 0, 0);
}

// ---------------------------------------------------------------------------
// K0 (fused prep): blocks [0,2048): transpose cb -> cbT fp32 + cbTh bf16;
// blocks [2048,2304): negC0[k] = -0.5*(||c_k||^2 + 1024);
// blocks [2304,2560): 3-way bf16 split of conv_w.
__global__ __launch_bounds__(256) void k_prep(const float* __restrict__ cb,
                                              const float* __restrict__ Wm,
                                              float* __restrict__ cbT,
                                              u16* __restrict__ cbTh,
                                              float* __restrict__ negC0,
                                              u16* __restrict__ wh,
                                              u16* __restrict__ wm,
                                              u16* __restrict__ wl) {
    int bx = blockIdx.x, tid = threadIdx.x;
    if (bx < 2048) {
        __shared__ float tile[32][33];
        int k0 = (bx & 255) * 32, d0 = (bx >> 8) * 32;
        int tx = tid & 31, ty = tid >> 5;  // 32 x 8
#pragma unroll
        for (int i = 0; i < 4; i++) {
            int d = d0 + ty + i * 8;
            tile[ty + i * 8][tx] = cb[d * KK + k0 + tx];
        }
        __syncthreads();
#pragma unroll
        for (int i = 0; i < 4; i++) {
            int k = k0 + ty + i * 8;
            float v = tile[tx][ty + i * 8];
            cbT[k * DD + d0 + tx] = v;
            cbTh[k * DD + d0 + tx] = f2b(v);
        }
    } else if (bx < 2304) {
        __shared__ float sm[8][32];
        int kl = tid & 31, dg = tid >> 5;
        int k = (bx - 2048) * 32 + kl;
        float s = 0.f;
#pragma unroll
        for (int j = 0; j < 32; j++) {
            float v = cb[(size_t)(dg * 32 + j) * KK + k];
            s += v * v;
        }
        sm[dg][kl] = s;
        __syncthreads();
        if (tid < 32) {
            float t = 0.f;
#pragma unroll
            for (int g = 0; g < 8; g++) t += sm[g][tid];
            negC0[(bx - 2048) * 32 + tid] = -0.5f * (t + 1024.f);
        }
    } else {
        int t = (bx - 2304) * 256 + tid;
        u16 h, m, l; split3(Wm[t], h, m, l);
        wh[t] = h; wm[t] = m; wl[t] = l;
    }
}

// ---------------------------------------------------------------------------
// K1: xp = x_r @ W^T + b via bf16x3 split MFMA (6 terms ~ fp32 accuracy).
// R12 structure: wave = 16 rows x 64 d (dt-quarter = wave id), grid NN/16.
__global__ __launch_bounds__(256) void k_proj(const float* __restrict__ x,
                                              const u16* __restrict__ wh,
                                              const u16* __restrict__ wm,
                                              const u16* __restrict__ wl,
                                              const float* __restrict__ bias,
                                              float* __restrict__ xp,
                                              u16* __restrict__ xpH) {
    int tid = threadIdx.x;
    int wave = tid >> 6, lane = tid & 63;    // wave = dt-quarter (0..3)
    int quad = lane >> 4, l15 = lane & 15;
    int n0 = blockIdx.x * 16;
    int n_a = n0 + l15;
    const float* xb = x + (n_a >> 10) * (CC * HW) + (n_a & (HW - 1));

    f32x4 acc[4];
#pragma unroll
    for (int i = 0; i < 4; i++) acc[i] = (f32x4){0.f, 0.f, 0.f, 0.f};

#pragma unroll
    for (int cc = 0; cc < 8; cc++) {
        bf16x8 ah, am, al;
#pragma unroll
        for (int j = 0; j < 8; j++) {
            float v = xb[(cc * 32 + quad * 8 + j) * HW];
            u16 h, m, l; split3(v, h, m, l);
            ah[j] = (short)h; am[j] = (short)m; al[j] = (short)l;
        }
#pragma unroll
        for (int dt = 0; dt < 4; dt++) {
            int dtg = wave * 4 + dt;
            int off = (dtg * 16 + l15) * CC + cc * 32 + quad * 8;
            const bf16x8 bh = *(const bf16x8*)(wh + off);
            const bf16x8 bm = *(const bf16x8*)(wm + off);
            const bf16x8 bl = *(const bf16x8*)(wl + off);
            acc[dt] = MFMA_BF16(ah, bh, acc[dt]);
            acc[dt] = MFMA_BF16(am, bh, acc[dt]);
            acc[dt] = MFMA_BF16(ah, bm, acc[dt]);
            acc[dt] = MFMA_BF16(al, bh, acc[dt]);
            acc[dt] = MFMA_BF16(am, bm, acc[dt]);
            acc[dt] = MFMA_BF16(ah, bl, acc[dt]);
        }
    }

#pragma unroll
    for (int dt = 0; dt < 4; dt++) {
        int d = (wave * 4 + dt) * 16 + l15;  // C-layout: col = lane&15
        float bv = bias[d];
#pragma unroll
        for (int r = 0; r < 4; r++) {
            int n = n0 + quad * 4 + r;       // C-layout: row = quad*4 + reg
            float v = acc[dt][r] + bv;
            xp[n * DD + d] = v;
            xpH[n * DD + d] = f2b(v);
        }
    }
}

// ---------------------------------------------------------------------------
// K2: approx distance GEMM (32x32x16 MFMA) + fused argmin-candidate select.
// R13: SINGLE change vs verified structure — per-2-row-chunk LDS stride
// 512 -> 516 u16 (1024 -> 1032 B). Mechanism: row bases were all multiples
// of 512 B = bank 0, so the B-read alias group {col, col+8, col+16, col+24}
// (same col&7 -> same XOR granule) hit the same 4-bank span: measured 4.0
// extra cycles per ds_read_b128 (8.39M conflicts). With 1032 B stride, row
// base bank = col&30 -> alias lanes' spans shift by 8/16/24 banks, disjoint.
// Write side unchanged: global_load_lds dst = chunk*516 (wave-uniform,
// linear 1 KB burst; 8 B pad untouched).
// C/D (verified m74/m101): col = lane&31, row = (reg&3)+8*(reg>>2)+4*(lane>>5).
__global__ __launch_bounds__(256, 3) void k_dist(const u16* __restrict__ xpH,
                                                 const u16* __restrict__ cbTh,
                                                 const float* __restrict__ negC0,
                                                 u32* __restrict__ pkey) {
    __shared__ __align__(16) u16 tile[2][16 * CH];  // 2 x 16.125 KB
    int tid = threadIdx.x, wave = tid >> 6, lane = tid & 63;
    int col = lane & 31, half = lane >> 5;
    int n0 = blockIdx.x * 128 + wave * 32;
    int ksbase = blockIdx.y * (KK / KSPLIT);   // 512 codes per split

    // A-frags resident: 16 ks (row = col, dims ks*16 + half*8 + j)
    bf16x8 Ah[16];
    {
        const u16* ab = xpH + (size_t)(n0 + col) * DD + half * 8;
#pragma unroll
        for (int ks = 0; ks < 16; ks++)
            Ah[ks] = *(const bf16x8*)(ab + ks * 16);
    }

    u32 key[16];
#pragma unroll
    for (int g = 0; g < 16; g++) key[g] = 0xffffffffu;

#define STAGE(bufi, kglob_)                                                    \
    {                                                                          \
        int kg_ = (kglob_);                                                    \
        _Pragma("unroll")                                                      \
        for (int c = 0; c < 4; c++) {                                          \
            int chunk = wave * 4 + c;                                          \
            int row = chunk * 2 + (lane >> 5);                                 \
            int g = (lane & 31) ^ (row & 7);                                   \
            const u16* src = cbTh + (size_t)(kg_ + row) * DD + g * 8;          \
            async_load16(src, &tile[bufi][chunk * CH]);                        \
        }                                                                      \
    }

    STAGE(0, ksbase);
    float nc_cur = negC0[ksbase + col];
    __syncthreads();

    for (int kc = 0; kc < 16; kc++) {
        int buf = kc & 1;
        float nc_next = 0.f;
        if (kc < 15) {
            STAGE(buf ^ 1, ksbase + (kc + 1) * KROWS);
            nc_next = negC0[ksbase + (kc + 1) * KROWS + col];
        }

        f32x16 a0, a1;
#pragma unroll
        for (int g = 0; g < 16; g++) { a0[g] = nc_cur; a1[g] = 0.f; }

        // row col lives in chunk col/2 at offset (col&1)*256 u16
        const u16* trow = &tile[buf][(col >> 1) * CH + (col & 1) * 256];
#pragma unroll
        for (int ks = 0; ks < 8; ks++) {
            int g0 = ((2 * ks) * 2 + half) ^ (col & 7);
            int g1 = ((2 * ks + 1) * 2 + half) ^ (col & 7);
            const bf16x8 Bf0 = *(const bf16x8*)(trow + g0 * 8);
            const bf16x8 Bf1 = *(const bf16x8*)(trow + g1 * 8);
            a0 = MFMA32_BF16(Ah[2 * ks], Bf0, a0);
            a1 = MFMA32_BF16(Ah[2 * ks + 1], Bf1, a1);
        }

        u32 orv = ((u32)kc << 5) | (u32)col;
#pragma unroll
        for (int g = 0; g < 16; g++) {
            u32 kb = (f2u(a0[g] + a1[g]) & 0xFFFFFE00u) | orv;
            key[g] = min(key[g], kb);
        }
        nc_cur = nc_next;
        __syncthreads();  // drains prefetch + guards buffers
    }
#undef STAGE

    // top-2 across the 32 lanes (cols) sharing each C row
#pragma unroll
    for (int g = 0; g < 16; g++) {
        u32 k1 = key[g], k2 = 0xffffffffu;
#pragma unroll
        for (int m = 1; m < 32; m <<= 1) {
            u32 o1 = (u32)__shfl_xor((int)k1, m, 64);
            u32 o2 = (u32)__shfl_xor((int)k2, m, 64);
            u32 mx = max(k1, o1);
            k1 = min(k1, o1);
            k2 = min(min(k2, o2), mx);
        }
        if (col == 0) {
            int row = (g & 3) + 8 * (g >> 2) + 4 * half;
            int n = n0 + row;
            int base = (n * KSPLIT + blockIdx.y) * 2;
            pkey[base]     = (u32)ksbase + (k1 & 511u);
            pkey[base + 1] = (u32)ksbase + (k2 & 511u);
        }
    }
}

// ---------------------------------------------------------------------------
// K3: exact fp64 rescore of 32 candidates per row. One wave per row, 4 serial
// groups (verified best: 79 us — R8 ILP and R10 TLP variants both regressed;
// bound by scattered-request throughput).
__global__ __launch_bounds__(256) void k_rescore(const float* __restrict__ xp,
                                                 const float* __restrict__ cbT,
                                                 const u32* __restrict__ pkey,
                                                 u32* __restrict__ idxv,
                                                 float* __restrict__ outIdx,
                                                 float* __restrict__ pmin) {
    int tid = threadIdx.x, wave = tid >> 6, lane = tid & 63;
    int n = blockIdx.x * 4 + wave;
    int sub = lane >> 3;
    int oct = lane & 7;

    f32x4 xv[8];
    const float* xb = xp + n * DD + oct * 32;
#pragma unroll
    for (int t = 0; t < 8; t++) xv[t] = *(const f32x4*)(xb + t * 4);

    u32 myk = pkey[n * 32 + (lane & 31)] & 8191u;

    double bestv = 1e300;
    u32 besti = 0u;
#pragma unroll
    for (int g = 0; g < 4; g++) {
        int c = g * 8 + sub;
        u32 kg = (u32)__shfl((int)myk, c, 64);
        const float* cv = cbT + kg * DD + oct * 32;
        double s = 0.0;
#pragma unroll
        for (int t = 0; t < 8; t++) {
            f32x4 cvv = *(const f32x4*)(cv + t * 4);
#pragma unroll
            for (int q = 0; q < 4; q++) {
                double d = (double)xv[t][q] - (double)cvv[q];
                s += d * d;
            }
        }
        s += __shfl_xor(s, 1, 64);
        s += __shfl_xor(s, 2, 64);
        s += __shfl_xor(s, 4, 64);
        if (s < bestv || (s == bestv && kg < besti)) { bestv = s; besti = kg; }
    }
#pragma unroll
    for (int m = 8; m < 64; m <<= 1) {
        double ov = __shfl_xor(bestv, m, 64);
        u32 oi = (u32)__shfl_xor((int)besti, m, 64);
        if (ov < bestv || (ov == bestv && oi < besti)) { bestv = ov; besti = oi; }
    }
    if (lane == 0) {
        idxv[n] = besti;
        outIdx[n] = (float)besti;
        pmin[n] = (float)bestv;
    }
}

// ---------------------------------------------------------------------------
// K4: diff = sum(pmin)/(N*D), fp64 (pmin in ws, no ordering constraint).
__global__ __launch_bounds__(1024) void k_final(const float* __restrict__ pmin,
                                                float* __restrict__ out) {
    __shared__ double sm[16];
    int tid = threadIdx.x, lane = tid & 63, wv = tid >> 6;
    double s = 0.0;
#pragma unroll
    for (int i = 0; i < 16; i++) s += (double)pmin[i * 1024 + tid];
#pragma unroll
    for (int m = 1; m < 64; m <<= 1) s += __shfl_xor(s, m, 64);
    if (lane == 0) sm[wv] = s;
    __syncthreads();
    if (tid == 0) {
        double t = 0.0;
#pragma unroll
        for (int i = 0; i < 16; i++) t += sm[i];
        out[0] = (float)(t * (1.0 / (double)OUT0));
    }
}

// ---------------------------------------------------------------------------
// K5: gather quantized (B,D,H,W) fp32 via LDS transpose tiles. Rewrites ALL
// of d_out chunk 0 (every scratch byte).
__global__ __launch_bounds__(256) void k_gather(const float* __restrict__ cbT,
                                                const u32* __restrict__ idxv,
                                                float* __restrict__ out0) {
    __shared__ float tile[32 * 260];
    int tid = threadIdx.x;
    int n0 = blockIdx.x * 32;
    int b = n0 >> 10, hw0 = n0 & 1023;

    {
        int r = tid >> 3, seg = tid & 7;
        u32 k = idxv[n0 + r] & 8191u;
        const float* src = cbT + k * DD + seg * 32;
        float* dst = tile + r * 260 + seg * 32;
#pragma unroll
        for (int j = 0; j < 8; j++)
            *(f32x4*)(dst + j * 4) = *(const f32x4*)(src + j * 4);
    }
    __syncthreads();
    {
        int hw = tid & 31, dq = tid >> 5;
        const float* trow = tile + hw * 260;
        float* obase = out0 + ((size_t)b * DD) * HW + hw0 + hw;
#pragma unroll
        for (int dj = 0; dj < 32; dj++) {
            int d = dq * 32 + dj;
            obase[(size_t)d * HW] = trow[d];
        }
    }
}

// ---------------------------------------------------------------------------
extern "C" void kernel_launch(void* const* d_in, const int* in_sizes, int n_in,
                              void* d_out, int out_size, void* d_ws, size_t ws_size,
                              hipStream_t stream) {
    const float* x = nullptr; const float* Wm = nullptr;
    const float* bias = nullptr; const float* cb = nullptr;
    for (int i = 0; i < n_in; i++) {
        switch (in_sizes[i]) {
            case 4194304: x    = (const float*)d_in[i]; break;  // (16,256,32,32)
            case 65536:   Wm   = (const float*)d_in[i]; break;  // (256,256)
            case 256:     bias = (const float*)d_in[i]; break;  // (256,)
            case 2097152: cb   = (const float*)d_in[i]; break;  // (256,8192)
        }
    }

    // d_out is FP32: [quantized (4194304) | diff (1) | indices (16384)]
    float* out0    = (float*)d_out;
    float* outDiff = (float*)d_out + OUT0;
    float* outIdx  = (float*)d_out + OUT0 + 1;

    // Transient scratch inside d_out chunk 0 (16.78 MB; every byte rewritten
    // by k_gather before the harness reads):
    char* o = (char*)d_out;
    u16*   cbTh = (u16*)o;                       // [0, 4 MB)
    u32*   pkey = (u32*)(o + 4194304);           // [4 MB, 6 MB)
    u16*   wh   = (u16*)(o + 6291456);           // 128 KB
    u16*   wm   = (u16*)(o + 6422528);           // 128 KB
    u16*   wl   = (u16*)(o + 6553600);           // 128 KB
    u16*   xpH  = (u16*)(o + 6750208);           // 8 MB  (N,D) bf16 -> ends 14.75 MB

    // Workspace (~25.33 MB, footprint that passed in rounds 4-9):
    char* w = (char*)d_ws;
    float* cbT   = (float*)(w);                  // 8 MB  (K,D) fp32
    float* xp    = (float*)(w + 8388608);        // 16 MB (N,D) fp32
    float* negC0 = (float*)(w + 25165824);       // 32 KB
    u32*   idxv  = (u32*)(w + 25198592);         // 64 KB
    float* pmin  = (float*)(w + 25264128);       // 64 KB

    k_prep<<<2560, 256, 0, stream>>>(cb, Wm, cbT, cbTh, negC0, wh, wm, wl);
    k_proj<<<NN / 16, 256, 0, stream>>>(x, wh, wm, wl, bias, xp, xpH);
    k_dist<<<dim3(NN / 128, KSPLIT), 256, 0, stream>>>(xpH, cbTh, negC0, pkey);
    k_rescore<<<NN / 4, 256, 0, stream>>>(xp, cbT, pkey, idxv, outIdx, pmin);
    k_final<<<1, 1024, 0, stream>>>(pmin, outDiff);
    k_gather<<<NN / 32, 256, 0, stream>>>(cbT, idxv, out0);
}

// Round 14
// 287.234 us; speedup vs baseline: 1.6828x; 1.6828x over previous
//
#include <hip/hip_runtime.h>

typedef short bf16x8 __attribute__((ext_vector_type(8)));
typedef float f32x4 __attribute__((ext_vector_type(4)));
typedef float f32x16 __attribute__((ext_vector_type(16)));
using u16 = unsigned short;
using u32 = unsigned int;

#define MFMA_BF16(A, B, C) __builtin_amdgcn_mfma_f32_16x16x32_bf16((A), (B), (C), 0, 0, 0)
#define MFMA32_BF16(A, B, C) __builtin_amdgcn_mfma_f32_32x32x16_bf16((A), (B), (C), 0, 0, 0)

#define CC 256
#define DD 256
#define KK 8192
#define NN 16384     // B*H*W
#define HW 1024      // H*W
#define OUT0 4194304 // B*D*H*W
#define KSPLIT 16
#define KROWS 32     // k-rows (codes) per LDS tile (verified best)

static __device__ __forceinline__ float b2f(u16 u) {
    union { u32 i; float f; } v; v.i = ((u32)u) << 16; return v.f;
}
static __device__ __forceinline__ u16 f2b(float f) {  // RNE fp32 -> bf16
    union { float f; u32 i; } v; v.f = f;
    u32 x = v.i;
    u32 r = (x + 0x7fffu + ((x >> 16) & 1u)) >> 16;
    return (u16)r;
}
static __device__ __forceinline__ u32 f2u(float f) {
    union { float f; u32 u; } v; v.f = f; return v.u;
}
static __device__ __forceinline__ void split3(float v, u16& h, u16& m, u16& l) {
    h = f2b(v); float r1 = v - b2f(h);
    m = f2b(r1); float r2 = r1 - b2f(m);
    l = f2b(r2);
}

typedef __attribute__((address_space(1))) const u32 GlbU32;
typedef __attribute__((address_space(3))) u32 LdsU32;
static __device__ __forceinline__ void async_load16(const void* g, void* l) {
    __builtin_amdgcn_global_load_lds((GlbU32*)g, (LdsU32*)l, 16, 0, 0);
}

// ---------------------------------------------------------------------------
// K0 (fused prep): blocks [0,2048): transpose cb -> cbT fp32 + cbTh bf16;
// blocks [2048,2304): negC0[k] = -0.5*(||c_k||^2 + 1024);
// blocks [2304,2560): 3-way bf16 split of conv_w.
__global__ __launch_bounds__(256) void k_prep(const float* __restrict__ cb,
                                              const float* __restrict__ Wm,
                                              float* __restrict__ cbT,
                                              u16* __restrict__ cbTh,
                                              float* __restrict__ negC0,
                                              u16* __restrict__ wh,
                                              u16* __restrict__ wm,
                                              u16* __restrict__ wl) {
    int bx = blockIdx.x, tid = threadIdx.x;
    if (bx < 2048) {
        __shared__ float tile[32][33];
        int k0 = (bx & 255) * 32, d0 = (bx >> 8) * 32;
        int tx = tid & 31, ty = tid >> 5;  // 32 x 8
#pragma unroll
        for (int i = 0; i < 4; i++) {
            int d = d0 + ty + i * 8;
            tile[ty + i * 8][tx] = cb[d * KK + k0 + tx];
        }
        __syncthreads();
#pragma unroll
        for (int i = 0; i < 4; i++) {
            int k = k0 + ty + i * 8;
            float v = tile[tx][ty + i * 8];
            cbT[k * DD + d0 + tx] = v;
            cbTh[k * DD + d0 + tx] = f2b(v);
        }
    } else if (bx < 2304) {
        __shared__ float sm[8][32];
        int kl = tid & 31, dg = tid >> 5;
        int k = (bx - 2048) * 32 + kl;
        float s = 0.f;
#pragma unroll
        for (int j = 0; j < 32; j++) {
            float v = cb[(size_t)(dg * 32 + j) * KK + k];
            s += v * v;
        }
        sm[dg][kl] = s;
        __syncthreads();
        if (tid < 32) {
            float t = 0.f;
#pragma unroll
            for (int g = 0; g < 8; g++) t += sm[g][tid];
            negC0[(bx - 2048) * 32 + tid] = -0.5f * (t + 1024.f);
        }
    } else {
        int t = (bx - 2304) * 256 + tid;
        u16 h, m, l; split3(Wm[t], h, m, l);
        wh[t] = h; wm[t] = m; wl[t] = l;
    }
}

// ---------------------------------------------------------------------------
// K1: xp = x_r @ W^T + b via bf16x3 split MFMA (6 terms ~ fp32 accuracy).
// R12 structure: wave = 16 rows x 64 d (dt-quarter = wave id), grid NN/16.
__global__ __launch_bounds__(256) void k_proj(const float* __restrict__ x,
                                              const u16* __restrict__ wh,
                                              const u16* __restrict__ wm,
                                              const u16* __restrict__ wl,
                                              const float* __restrict__ bias,
                                              float* __restrict__ xp,
                                              u16* __restrict__ xpH) {
    int tid = threadIdx.x;
    int wave = tid >> 6, lane = tid & 63;    // wave = dt-quarter (0..3)
    int quad = lane >> 4, l15 = lane & 15;
    int n0 = blockIdx.x * 16;
    int n_a = n0 + l15;
    const float* xb = x + (n_a >> 10) * (CC * HW) + (n_a & (HW - 1));

    f32x4 acc[4];
#pragma unroll
    for (int i = 0; i < 4; i++) acc[i] = (f32x4){0.f, 0.f, 0.f, 0.f};

#pragma unroll
    for (int cc = 0; cc < 8; cc++) {
        bf16x8 ah, am, al;
#pragma unroll
        for (int j = 0; j < 8; j++) {
            float v = xb[(cc * 32 + quad * 8 + j) * HW];
            u16 h, m, l; split3(v, h, m, l);
            ah[j] = (short)h; am[j] = (short)m; al[j] = (short)l;
        }
#pragma unroll
        for (int dt = 0; dt < 4; dt++) {
            int dtg = wave * 4 + dt;
            int off = (dtg * 16 + l15) * CC + cc * 32 + quad * 8;
            const bf16x8 bh = *(const bf16x8*)(wh + off);
            const bf16x8 bm = *(const bf16x8*)(wm + off);
            const bf16x8 bl = *(const bf16x8*)(wl + off);
            acc[dt] = MFMA_BF16(ah, bh, acc[dt]);
            acc[dt] = MFMA_BF16(am, bh, acc[dt]);
            acc[dt] = MFMA_BF16(ah, bm, acc[dt]);
            acc[dt] = MFMA_BF16(al, bh, acc[dt]);
            acc[dt] = MFMA_BF16(am, bm, acc[dt]);
            acc[dt] = MFMA_BF16(ah, bl, acc[dt]);
        }
    }

#pragma unroll
    for (int dt = 0; dt < 4; dt++) {
        int d = (wave * 4 + dt) * 16 + l15;  // C-layout: col = lane&15
        float bv = bias[d];
#pragma unroll
        for (int r = 0; r < 4; r++) {
            int n = n0 + quad * 4 + r;       // C-layout: row = quad*4 + reg
            float v = acc[dt][r] + bv;
            xp[n * DD + d] = v;
            xpH[n * DD + d] = f2b(v);
        }
    }
}

// ---------------------------------------------------------------------------
// K2: approx distance GEMM (32x32x16 MFMA) + fused argmin-candidate select.
// REVERTED to the verified best structure (R12, 94 us): KROWS=32, XOR
// swizzle, 512-u16 chunk stride (16B-aligned), 2 LDS buffers, __syncthreads
// per kc, mt=1, ILP-2 MFMA chains. R13's de-bank pad proved the 4-way read
// conflict is STRUCTURAL under global_load_lds's wave-uniform linear dest
// (16B pad granularity = 4 banks preserves the alias tie; 8B pads break
// alignment -> 3x slow path). 8 k_dist experiments, all regressed: this is
// the local optimum. C/D: col = lane&31, row = (reg&3)+8*(reg>>2)+4*(lane>>5).
__global__ __launch_bounds__(256, 3) void k_dist(const u16* __restrict__ xpH,
                                                 const u16* __restrict__ cbTh,
                                                 const float* __restrict__ negC0,
                                                 u32* __restrict__ pkey) {
    __shared__ __align__(16) u16 tile[2][KROWS * 256];  // 2 x 16 KB
    int tid = threadIdx.x, wave = tid >> 6, lane = tid & 63;
    int col = lane & 31, half = lane >> 5;
    int n0 = blockIdx.x * 128 + wave * 32;
    int ksbase = blockIdx.y * (KK / KSPLIT);   // 512 codes per split

    // A-frags resident: 16 ks (row = col, dims ks*16 + half*8 + j)
    bf16x8 Ah[16];
    {
        const u16* ab = xpH + (size_t)(n0 + col) * DD + half * 8;
#pragma unroll
        for (int ks = 0; ks < 16; ks++)
            Ah[ks] = *(const bf16x8*)(ab + ks * 16);
    }

    u32 key[16];
#pragma unroll
    for (int g = 0; g < 16; g++) key[g] = 0xffffffffu;

#define STAGE(bufi, kglob_)                                                    \
    {                                                                          \
        int kg_ = (kglob_);                                                    \
        _Pragma("unroll")                                                      \
        for (int c = 0; c < 4; c++) {                                          \
            int chunk = wave * 4 + c;                                          \
            int row = chunk * 2 + (lane >> 5);                                 \
            int g = (lane & 31) ^ (row & 7);                                   \
            const u16* src = cbTh + (size_t)(kg_ + row) * DD + g * 8;          \
            async_load16(src, &tile[bufi][chunk * 512]);                       \
        }                                                                      \
    }

    STAGE(0, ksbase);
    float nc_cur = negC0[ksbase + col];
    __syncthreads();

    for (int kc = 0; kc < 16; kc++) {
        int buf = kc & 1;
        float nc_next = 0.f;
        if (kc < 15) {
            STAGE(buf ^ 1, ksbase + (kc + 1) * KROWS);
            nc_next = negC0[ksbase + (kc + 1) * KROWS + col];
        }

        f32x16 a0, a1;
#pragma unroll
        for (int g = 0; g < 16; g++) { a0[g] = nc_cur; a1[g] = 0.f; }

        const u16* trow = &tile[buf][col * 256];
#pragma unroll
        for (int ks = 0; ks < 8; ks++) {
            int g0 = ((2 * ks) * 2 + half) ^ (col & 7);
            int g1 = ((2 * ks + 1) * 2 + half) ^ (col & 7);
            const bf16x8 Bf0 = *(const bf16x8*)(trow + g0 * 8);
            const bf16x8 Bf1 = *(const bf16x8*)(trow + g1 * 8);
            a0 = MFMA32_BF16(Ah[2 * ks], Bf0, a0);
            a1 = MFMA32_BF16(Ah[2 * ks + 1], Bf1, a1);
        }

        u32 orv = ((u32)kc << 5) | (u32)col;
#pragma unroll
        for (int g = 0; g < 16; g++) {
            u32 kb = (f2u(a0[g] + a1[g]) & 0xFFFFFE00u) | orv;
            key[g] = min(key[g], kb);
        }
        nc_cur = nc_next;
        __syncthreads();  // drains prefetch + guards buffers
    }
#undef STAGE

    // top-2 across the 32 lanes (cols) sharing each C row
#pragma unroll
    for (int g = 0; g < 16; g++) {
        u32 k1 = key[g], k2 = 0xffffffffu;
#pragma unroll
        for (int m = 1; m < 32; m <<= 1) {
            u32 o1 = (u32)__shfl_xor((int)k1, m, 64);
            u32 o2 = (u32)__shfl_xor((int)k2, m, 64);
            u32 mx = max(k1, o1);
            k1 = min(k1, o1);
            k2 = min(min(k2, o2), mx);
        }
        if (col == 0) {
            int row = (g & 3) + 8 * (g >> 2) + 4 * half;
            int n = n0 + row;
            int base = (n * KSPLIT + blockIdx.y) * 2;
            pkey[base]     = (u32)ksbase + (k1 & 511u);
            pkey[base + 1] = (u32)ksbase + (k2 & 511u);
        }
    }
}

// ---------------------------------------------------------------------------
// K3: exact fp64 rescore of 32 candidates per row. One wave per row, 4 serial
// groups (verified best: 79 us — R8 ILP and R10 TLP variants both regressed;
// bound by scattered-request throughput).
__global__ __launch_bounds__(256) void k_rescore(const float* __restrict__ xp,
                                                 const float* __restrict__ cbT,
                                                 const u32* __restrict__ pkey,
                                                 u32* __restrict__ idxv,
                                                 float* __restrict__ outIdx,
                                                 float* __restrict__ pmin) {
    int tid = threadIdx.x, wave = tid >> 6, lane = tid & 63;
    int n = blockIdx.x * 4 + wave;
    int sub = lane >> 3;
    int oct = lane & 7;

    f32x4 xv[8];
    const float* xb = xp + n * DD + oct * 32;
#pragma unroll
    for (int t = 0; t < 8; t++) xv[t] = *(const f32x4*)(xb + t * 4);

    u32 myk = pkey[n * 32 + (lane & 31)] & 8191u;

    double bestv = 1e300;
    u32 besti = 0u;
#pragma unroll
    for (int g = 0; g < 4; g++) {
        int c = g * 8 + sub;
        u32 kg = (u32)__shfl((int)myk, c, 64);
        const float* cv = cbT + kg * DD + oct * 32;
        double s = 0.0;
#pragma unroll
        for (int t = 0; t < 8; t++) {
            f32x4 cvv = *(const f32x4*)(cv + t * 4);
#pragma unroll
            for (int q = 0; q < 4; q++) {
                double d = (double)xv[t][q] - (double)cvv[q];
                s += d * d;
            }
        }
        s += __shfl_xor(s, 1, 64);
        s += __shfl_xor(s, 2, 64);
        s += __shfl_xor(s, 4, 64);
        if (s < bestv || (s == bestv && kg < besti)) { bestv = s; besti = kg; }
    }
#pragma unroll
    for (int m = 8; m < 64; m <<= 1) {
        double ov = __shfl_xor(bestv, m, 64);
        u32 oi = (u32)__shfl_xor((int)besti, m, 64);
        if (ov < bestv || (ov == bestv && oi < besti)) { bestv = ov; besti = oi; }
    }
    if (lane == 0) {
        idxv[n] = besti;
        outIdx[n] = (float)besti;
        pmin[n] = (float)bestv;
    }
}

// ---------------------------------------------------------------------------
// K5 (R14: k_final folded in): gather quantized (B,D,H,W) fp32 via LDS
// transpose tiles; the one extra block (blockIdx.x == NN/32) instead reduces
// pmin -> outDiff (independent work, runs concurrently; saves one dispatch).
// Rewrites ALL of d_out chunk 0 (every scratch byte).
__global__ __launch_bounds__(256) void k_gather(const float* __restrict__ cbT,
                                                const u32* __restrict__ idxv,
                                                const float* __restrict__ pmin,
                                                float* __restrict__ out0,
                                                float* __restrict__ outDiff) {
    if (blockIdx.x == NN / 32) {
        // fused k_final: diff = sum(pmin)/(N*D), fp64. 256 threads x 64 vals.
        __shared__ double sm[4];
        int tid = threadIdx.x, lane = tid & 63, wv = tid >> 6;
        double s = 0.0;
#pragma unroll
        for (int i = 0; i < 64; i++) s += (double)pmin[i * 256 + tid];
#pragma unroll
        for (int m = 1; m < 64; m <<= 1) s += __shfl_xor(s, m, 64);
        if (lane == 0) sm[wv] = s;
        __syncthreads();
        if (tid == 0)
            outDiff[0] = (float)((sm[0] + sm[1] + sm[2] + sm[3]) * (1.0 / (double)OUT0));
        return;
    }

    __shared__ float tile[32 * 260];
    int tid = threadIdx.x;
    int n0 = blockIdx.x * 32;
    int b = n0 >> 10, hw0 = n0 & 1023;

    {
        int r = tid >> 3, seg = tid & 7;
        u32 k = idxv[n0 + r] & 8191u;
        const float* src = cbT + k * DD + seg * 32;
        float* dst = tile + r * 260 + seg * 32;
#pragma unroll
        for (int j = 0; j < 8; j++)
            *(f32x4*)(dst + j * 4) = *(const f32x4*)(src + j * 4);
    }
    __syncthreads();
    {
        int hw = tid & 31, dq = tid >> 5;
        const float* trow = tile + hw * 260;
        float* obase = out0 + ((size_t)b * DD) * HW + hw0 + hw;
#pragma unroll
        for (int dj = 0; dj < 32; dj++) {
            int d = dq * 32 + dj;
            obase[(size_t)d * HW] = trow[d];
        }
    }
}

// ---------------------------------------------------------------------------
extern "C" void kernel_launch(void* const* d_in, const int* in_sizes, int n_in,
                              void* d_out, int out_size, void* d_ws, size_t ws_size,
                              hipStream_t stream) {
    const float* x = nullptr; const float* Wm = nullptr;
    const float* bias = nullptr; const float* cb = nullptr;
    for (int i = 0; i < n_in; i++) {
        switch (in_sizes[i]) {
            case 4194304: x    = (const float*)d_in[i]; break;  // (16,256,32,32)
            case 65536:   Wm   = (const float*)d_in[i]; break;  // (256,256)
            case 256:     bias = (const float*)d_in[i]; break;  // (256,)
            case 2097152: cb   = (const float*)d_in[i]; break;  // (256,8192)
        }
    }

    // d_out is FP32: [quantized (4194304) | diff (1) | indices (16384)]
    float* out0    = (float*)d_out;
    float* outDiff = (float*)d_out + OUT0;
    float* outIdx  = (float*)d_out + OUT0 + 1;

    // Transient scratch inside d_out chunk 0 (16.78 MB; every byte rewritten
    // by k_gather before the harness reads):
    char* o = (char*)d_out;
    u16*   cbTh = (u16*)o;                       // [0, 4 MB)
    u32*   pkey = (u32*)(o + 4194304);           // [4 MB, 6 MB)
    u16*   wh   = (u16*)(o + 6291456);           // 128 KB
    u16*   wm   = (u16*)(o + 6422528);           // 128 KB
    u16*   wl   = (u16*)(o + 6553600);           // 128 KB
    u16*   xpH  = (u16*)(o + 6750208);           // 8 MB  (N,D) bf16 -> ends 14.75 MB

    // Workspace (~25.33 MB, footprint that passed in rounds 4-9):
    char* w = (char*)d_ws;
    float* cbT   = (float*)(w);                  // 8 MB  (K,D) fp32
    float* xp    = (float*)(w + 8388608);        // 16 MB (N,D) fp32
    float* negC0 = (float*)(w + 25165824);       // 32 KB
    u32*   idxv  = (u32*)(w + 25198592);         // 64 KB
    float* pmin  = (float*)(w + 25264128);       // 64 KB

    k_prep<<<2560, 256, 0, stream>>>(cb, Wm, cbT, cbTh, negC0, wh, wm, wl);
    k_proj<<<NN / 16, 256, 0, stream>>>(x, wh, wm, wl, bias, xp, xpH);
    k_dist<<<dim3(NN / 128, KSPLIT), 256, 0, stream>>>(xpH, cbTh, negC0, pkey);
    k_rescore<<<NN / 4, 256, 0, stream>>>(xp, cbT, pkey, idxv, outIdx, pmin);
    k_gather<<<NN / 32 + 1, 256, 0, stream>>>(cbT, idxv, pmin, out0, outDiff);
}

// Round 15
// 261.116 us; speedup vs baseline: 1.8511x; 1.1000x over previous
//
#include <hip/hip_runtime.h>

typedef short bf16x8 __attribute__((ext_vector_type(8)));
typedef float f32x4 __attribute__((ext_vector_type(4)));
typedef float f32x16 __attribute__((ext_vector_type(16)));
using u16 = unsigned short;
using u32 = unsigned int;

#define MFMA_BF16(A, B, C) __builtin_amdgcn_mfma_f32_16x16x32_bf16((A), (B), (C), 0, 0, 0)
#define MFMA32_BF16(A, B, C) __builtin_amdgcn_mfma_f32_32x32x16_bf16((A), (B), (C), 0, 0, 0)

#define CC 256
#define DD 256
#define KK 8192
#define NN 16384     // B*H*W
#define HW 1024      // H*W
#define OUT0 4194304 // B*D*H*W
#define KSPLIT 16
#define KROWS 32     // k-rows (codes) per LDS tile (verified best)

static __device__ __forceinline__ float b2f(u16 u) {
    union { u32 i; float f; } v; v.i = ((u32)u) << 16; return v.f;
}
static __device__ __forceinline__ u16 f2b(float f) {  // RNE fp32 -> bf16
    union { float f; u32 i; } v; v.f = f;
    u32 x = v.i;
    u32 r = (x + 0x7fffu + ((x >> 16) & 1u)) >> 16;
    return (u16)r;
}
static __device__ __forceinline__ u32 f2u(float f) {
    union { float f; u32 u; } v; v.f = f; return v.u;
}
static __device__ __forceinline__ void split3(float v, u16& h, u16& m, u16& l) {
    h = f2b(v); float r1 = v - b2f(h);
    m = f2b(r1); float r2 = r1 - b2f(m);
    l = f2b(r2);
}

typedef __attribute__((address_space(1))) const u32 GlbU32;
typedef __attribute__((address_space(3))) u32 LdsU32;
static __device__ __forceinline__ void async_load16(const void* g, void* l) {
    __builtin_amdgcn_global_load_lds((GlbU32*)g, (LdsU32*)l, 16, 0, 0);
}

// ---------------------------------------------------------------------------
// K0 (fused prep): blocks [0,2048): transpose cb -> cbT fp32 + cbTh bf16;
// blocks [2048,2304): negC0[k] = -0.5*(||c_k||^2 + 1024);
// blocks [2304,2560): 3-way bf16 split of conv_w.
__global__ __launch_bounds__(256) void k_prep(const float* __restrict__ cb,
                                              const float* __restrict__ Wm,
                                              float* __restrict__ cbT,
                                              u16* __restrict__ cbTh,
                                              float* __restrict__ negC0,
                                              u16* __restrict__ wh,
                                              u16* __restrict__ wm,
                                              u16* __restrict__ wl) {
    int bx = blockIdx.x, tid = threadIdx.x;
    if (bx < 2048) {
        __shared__ float tile[32][33];
        int k0 = (bx & 255) * 32, d0 = (bx >> 8) * 32;
        int tx = tid & 31, ty = tid >> 5;  // 32 x 8
#pragma unroll
        for (int i = 0; i < 4; i++) {
            int d = d0 + ty + i * 8;
            tile[ty + i * 8][tx] = cb[d * KK + k0 + tx];
        }
        __syncthreads();
#pragma unroll
        for (int i = 0; i < 4; i++) {
            int k = k0 + ty + i * 8;
            float v = tile[tx][ty + i * 8];
            cbT[k * DD + d0 + tx] = v;
            cbTh[k * DD + d0 + tx] = f2b(v);
        }
    } else if (bx < 2304) {
        __shared__ float sm[8][32];
        int kl = tid & 31, dg = tid >> 5;
        int k = (bx - 2048) * 32 + kl;
        float s = 0.f;
#pragma unroll
        for (int j = 0; j < 32; j++) {
            float v = cb[(size_t)(dg * 32 + j) * KK + k];
            s += v * v;
        }
        sm[dg][kl] = s;
        __syncthreads();
        if (tid < 32) {
            float t = 0.f;
#pragma unroll
            for (int g = 0; g < 8; g++) t += sm[g][tid];
            negC0[(bx - 2048) * 32 + tid] = -0.5f * (t + 1024.f);
        }
    } else {
        int t = (bx - 2304) * 256 + tid;
        u16 h, m, l; split3(Wm[t], h, m, l);
        wh[t] = h; wm[t] = m; wl[t] = l;
    }
}

// ---------------------------------------------------------------------------
// K1: xp = x_r @ W^T + b via bf16x3 split MFMA (6 terms ~ fp32 accuracy).
// R12 structure: wave = 16 rows x 64 d (dt-quarter = wave id), grid NN/16.
__global__ __launch_bounds__(256) void k_proj(const float* __restrict__ x,
                                              const u16* __restrict__ wh,
                                              const u16* __restrict__ wm,
                                              const u16* __restrict__ wl,
                                              const float* __restrict__ bias,
                                              float* __restrict__ xp,
                                              u16* __restrict__ xpH) {
    int tid = threadIdx.x;
    int wave = tid >> 6, lane = tid & 63;    // wave = dt-quarter (0..3)
    int quad = lane >> 4, l15 = lane & 15;
    int n0 = blockIdx.x * 16;
    int n_a = n0 + l15;
    const float* xb = x + (n_a >> 10) * (CC * HW) + (n_a & (HW - 1));

    f32x4 acc[4];
#pragma unroll
    for (int i = 0; i < 4; i++) acc[i] = (f32x4){0.f, 0.f, 0.f, 0.f};

#pragma unroll
    for (int cc = 0; cc < 8; cc++) {
        bf16x8 ah, am, al;
#pragma unroll
        for (int j = 0; j < 8; j++) {
            float v = xb[(cc * 32 + quad * 8 + j) * HW];
            u16 h, m, l; split3(v, h, m, l);
            ah[j] = (short)h; am[j] = (short)m; al[j] = (short)l;
        }
#pragma unroll
        for (int dt = 0; dt < 4; dt++) {
            int dtg = wave * 4 + dt;
            int off = (dtg * 16 + l15) * CC + cc * 32 + quad * 8;
            const bf16x8 bh = *(const bf16x8*)(wh + off);
            const bf16x8 bm = *(const bf16x8*)(wm + off);
            const bf16x8 bl = *(const bf16x8*)(wl + off);
            acc[dt] = MFMA_BF16(ah, bh, acc[dt]);
            acc[dt] = MFMA_BF16(am, bh, acc[dt]);
            acc[dt] = MFMA_BF16(ah, bm, acc[dt]);
            acc[dt] = MFMA_BF16(al, bh, acc[dt]);
            acc[dt] = MFMA_BF16(am, bm, acc[dt]);
            acc[dt] = MFMA_BF16(ah, bl, acc[dt]);
        }
    }

#pragma unroll
    for (int dt = 0; dt < 4; dt++) {
        int d = (wave * 4 + dt) * 16 + l15;  // C-layout: col = lane&15
        float bv = bias[d];
#pragma unroll
        for (int r = 0; r < 4; r++) {
            int n = n0 + quad * 4 + r;       // C-layout: row = quad*4 + reg
            float v = acc[dt][r] + bv;
            xp[n * DD + d] = v;
            xpH[n * DD + d] = f2b(v);
        }
    }
}

// ---------------------------------------------------------------------------
// K2: approx distance GEMM (32x32x16 MFMA) + fused argmin-candidate select.
// Verified best structure: KROWS=32, XOR swizzle, 512-u16 chunk stride,
// 2 LDS buffers, __syncthreads per kc, mt=1, ILP-2 MFMA chains. 8 structural
// experiments all regressed — measured local optimum.
// C/D (verified m74/m101): col = lane&31, row = (reg&3)+8*(reg>>2)+4*(lane>>5).
__global__ __launch_bounds__(256, 3) void k_dist(const u16* __restrict__ xpH,
                                                 const u16* __restrict__ cbTh,
                                                 const float* __restrict__ negC0,
                                                 u32* __restrict__ pkey) {
    __shared__ __align__(16) u16 tile[2][KROWS * 256];  // 2 x 16 KB
    int tid = threadIdx.x, wave = tid >> 6, lane = tid & 63;
    int col = lane & 31, half = lane >> 5;
    int n0 = blockIdx.x * 128 + wave * 32;
    int ksbase = blockIdx.y * (KK / KSPLIT);   // 512 codes per split

    // A-frags resident: 16 ks (row = col, dims ks*16 + half*8 + j)
    bf16x8 Ah[16];
    {
        const u16* ab = xpH + (size_t)(n0 + col) * DD + half * 8;
#pragma unroll
        for (int ks = 0; ks < 16; ks++)
            Ah[ks] = *(const bf16x8*)(ab + ks * 16);
    }

    u32 key[16];
#pragma unroll
    for (int g = 0; g < 16; g++) key[g] = 0xffffffffu;

#define STAGE(bufi, kglob_)                                                    \
    {                                                                          \
        int kg_ = (kglob_);                                                    \
        _Pragma("unroll")                                                      \
        for (int c = 0; c < 4; c++) {                                          \
            int chunk = wave * 4 + c;                                          \
            int row = chunk * 2 + (lane >> 5);                                 \
            int g = (lane & 31) ^ (row & 7);                                   \
            const u16* src = cbTh + (size_t)(kg_ + row) * DD + g * 8;          \
            async_load16(src, &tile[bufi][chunk * 512]);                       \
        }                                                                      \
    }

    STAGE(0, ksbase);
    float nc_cur = negC0[ksbase + col];
    __syncthreads();

    for (int kc = 0; kc < 16; kc++) {
        int buf = kc & 1;
        float nc_next = 0.f;
        if (kc < 15) {
            STAGE(buf ^ 1, ksbase + (kc + 1) * KROWS);
            nc_next = negC0[ksbase + (kc + 1) * KROWS + col];
        }

        f32x16 a0, a1;
#pragma unroll
        for (int g = 0; g < 16; g++) { a0[g] = nc_cur; a1[g] = 0.f; }

        const u16* trow = &tile[buf][col * 256];
#pragma unroll
        for (int ks = 0; ks < 8; ks++) {
            int g0 = ((2 * ks) * 2 + half) ^ (col & 7);
            int g1 = ((2 * ks + 1) * 2 + half) ^ (col & 7);
            const bf16x8 Bf0 = *(const bf16x8*)(trow + g0 * 8);
            const bf16x8 Bf1 = *(const bf16x8*)(trow + g1 * 8);
            a0 = MFMA32_BF16(Ah[2 * ks], Bf0, a0);
            a1 = MFMA32_BF16(Ah[2 * ks + 1], Bf1, a1);
        }

        u32 orv = ((u32)kc << 5) | (u32)col;
#pragma unroll
        for (int g = 0; g < 16; g++) {
            u32 kb = (f2u(a0[g] + a1[g]) & 0xFFFFFE00u) | orv;
            key[g] = min(key[g], kb);
        }
        nc_cur = nc_next;
        __syncthreads();  // drains prefetch + guards buffers
    }
#undef STAGE

    // top-2 across the 32 lanes (cols) sharing each C row
#pragma unroll
    for (int g = 0; g < 16; g++) {
        u32 k1 = key[g], k2 = 0xffffffffu;
#pragma unroll
        for (int m = 1; m < 32; m <<= 1) {
            u32 o1 = (u32)__shfl_xor((int)k1, m, 64);
            u32 o2 = (u32)__shfl_xor((int)k2, m, 64);
            u32 mx = max(k1, o1);
            k1 = min(k1, o1);
            k2 = min(min(k2, o2), mx);
        }
        if (col == 0) {
            int row = (g & 3) + 8 * (g >> 2) + 4 * half;
            int n = n0 + row;
            int base = (n * KSPLIT + blockIdx.y) * 2;
            pkey[base]     = (u32)ksbase + (k1 & 511u);
            pkey[base + 1] = (u32)ksbase + (k2 & 511u);
        }
    }
}

// ---------------------------------------------------------------------------
// K3: exact fp64 rescore of 32 candidates per row. One wave per row, 4 serial
// groups. R15: COALESCING FIX — element partition among the 8 lanes of a
// sub-group changed from (oct*32 + t*4) to ((t*8 + oct)*4): each load
// instruction now covers a CONTIGUOUS 128 B span per candidate row (8 x 128 B
// transactions) instead of 64 scattered 16 B transactions. Same bytes, 8x
// fewer requests — attacks the measured scattered-request-throughput bound
// (R9: VALUBusy 17.7%, nothing saturated; R8 ILP / R10 TLP both regressed).
// Lane->element partition is arbitrary for the distance sum (fp64 partials,
// shfl-reduced); values identical to ~1e-16, comparator unchanged.
__global__ __launch_bounds__(256) void k_rescore(const float* __restrict__ xp,
                                                 const float* __restrict__ cbT,
                                                 const u32* __restrict__ pkey,
                                                 u32* __restrict__ idxv,
                                                 float* __restrict__ outIdx,
                                                 float* __restrict__ pmin) {
    int tid = threadIdx.x, wave = tid >> 6, lane = tid & 63;
    int n = blockIdx.x * 4 + wave;
    int sub = lane >> 3;
    int oct = lane & 7;

    f32x4 xv[8];
    const float* xb = xp + n * DD;
#pragma unroll
    for (int t = 0; t < 8; t++) xv[t] = *(const f32x4*)(xb + (t * 8 + oct) * 4);

    u32 myk = pkey[n * 32 + (lane & 31)] & 8191u;

    double bestv = 1e300;
    u32 besti = 0u;
#pragma unroll
    for (int g = 0; g < 4; g++) {
        int c = g * 8 + sub;
        u32 kg = (u32)__shfl((int)myk, c, 64);
        const float* cv = cbT + (size_t)kg * DD;
        double s = 0.0;
#pragma unroll
        for (int t = 0; t < 8; t++) {
            f32x4 cvv = *(const f32x4*)(cv + (t * 8 + oct) * 4);
#pragma unroll
            for (int q = 0; q < 4; q++) {
                double d = (double)xv[t][q] - (double)cvv[q];
                s += d * d;
            }
        }
        s += __shfl_xor(s, 1, 64);
        s += __shfl_xor(s, 2, 64);
        s += __shfl_xor(s, 4, 64);
        if (s < bestv || (s == bestv && kg < besti)) { bestv = s; besti = kg; }
    }
#pragma unroll
    for (int m = 8; m < 64; m <<= 1) {
        double ov = __shfl_xor(bestv, m, 64);
        u32 oi = (u32)__shfl_xor((int)besti, m, 64);
        if (ov < bestv || (ov == bestv && oi < besti)) { bestv = ov; besti = oi; }
    }
    if (lane == 0) {
        idxv[n] = besti;
        outIdx[n] = (float)besti;
        pmin[n] = (float)bestv;
    }
}

// ---------------------------------------------------------------------------
// K5 (k_final folded in): gather quantized (B,D,H,W) fp32 via LDS transpose
// tiles; block NN/32 reduces pmin -> outDiff. R15: same coalescing fix on
// the cbT staging reads (seg<->j roles swapped; tile contents identical
// element-for-element). Rewrites ALL of d_out chunk 0.
__global__ __launch_bounds__(256) void k_gather(const float* __restrict__ cbT,
                                                const u32* __restrict__ idxv,
                                                const float* __restrict__ pmin,
                                                float* __restrict__ out0,
                                                float* __restrict__ outDiff) {
    if (blockIdx.x == NN / 32) {
        // fused k_final: diff = sum(pmin)/(N*D), fp64. 256 threads x 64 vals.
        __shared__ double sm[4];
        int tid = threadIdx.x, lane = tid & 63, wv = tid >> 6;
        double s = 0.0;
#pragma unroll
        for (int i = 0; i < 64; i++) s += (double)pmin[i * 256 + tid];
#pragma unroll
        for (int m = 1; m < 64; m <<= 1) s += __shfl_xor(s, m, 64);
        if (lane == 0) sm[wv] = s;
        __syncthreads();
        if (tid == 0)
            outDiff[0] = (float)((sm[0] + sm[1] + sm[2] + sm[3]) * (1.0 / (double)OUT0));
        return;
    }

    __shared__ float tile[32 * 260];
    int tid = threadIdx.x;
    int n0 = blockIdx.x * 32;
    int b = n0 >> 10, hw0 = n0 & 1023;

    {
        int r = tid >> 3, seg = tid & 7;
        u32 k = idxv[n0 + r] & 8191u;
        const float* src = cbT + (size_t)k * DD;
        float* dst = tile + r * 260;
#pragma unroll
        for (int j = 0; j < 8; j++)
            *(f32x4*)(dst + (j * 8 + seg) * 4) = *(const f32x4*)(src + (j * 8 + seg) * 4);
    }
    __syncthreads();
    {
        int hw = tid & 31, dq = tid >> 5;
        const float* trow = tile + hw * 260;
        float* obase = out0 + ((size_t)b * DD) * HW + hw0 + hw;
#pragma unroll
        for (int dj = 0; dj < 32; dj++) {
            int d = dq * 32 + dj;
            obase[(size_t)d * HW] = trow[d];
        }
    }
}

// ---------------------------------------------------------------------------
extern "C" void kernel_launch(void* const* d_in, const int* in_sizes, int n_in,
                              void* d_out, int out_size, void* d_ws, size_t ws_size,
                              hipStream_t stream) {
    const float* x = nullptr; const float* Wm = nullptr;
    const float* bias = nullptr; const float* cb = nullptr;
    for (int i = 0; i < n_in; i++) {
        switch (in_sizes[i]) {
            case 4194304: x    = (const float*)d_in[i]; break;  // (16,256,32,32)
            case 65536:   Wm   = (const float*)d_in[i]; break;  // (256,256)
            case 256:     bias = (const float*)d_in[i]; break;  // (256,)
            case 2097152: cb   = (const float*)d_in[i]; break;  // (256,8192)
        }
    }

    // d_out is FP32: [quantized (4194304) | diff (1) | indices (16384)]
    float* out0    = (float*)d_out;
    float* outDiff = (float*)d_out + OUT0;
    float* outIdx  = (float*)d_out + OUT0 + 1;

    // Transient scratch inside d_out chunk 0 (16.78 MB; every byte rewritten
    // by k_gather before the harness reads):
    char* o = (char*)d_out;
    u16*   cbTh = (u16*)o;                       // [0, 4 MB)
    u32*   pkey = (u32*)(o + 4194304);           // [4 MB, 6 MB)
    u16*   wh   = (u16*)(o + 6291456);           // 128 KB
    u16*   wm   = (u16*)(o + 6422528);           // 128 KB
    u16*   wl   = (u16*)(o + 6553600);           // 128 KB
    u16*   xpH  = (u16*)(o + 6750208);           // 8 MB  (N,D) bf16 -> ends 14.75 MB

    // Workspace (~25.33 MB, footprint that passed in rounds 4-9):
    char* w = (char*)d_ws;
    float* cbT   = (float*)(w);                  // 8 MB  (K,D) fp32
    float* xp    = (float*)(w + 8388608);        // 16 MB (N,D) fp32
    float* negC0 = (float*)(w + 25165824);       // 32 KB
    u32*   idxv  = (u32*)(w + 25198592);         // 64 KB
    float* pmin  = (float*)(w + 25264128);       // 64 KB

    k_prep<<<2560, 256, 0, stream>>>(cb, Wm, cbT, cbTh, negC0, wh, wm, wl);
    k_proj<<<NN / 16, 256, 0, stream>>>(x, wh, wm, wl, bias, xp, xpH);
    k_dist<<<dim3(NN / 128, KSPLIT), 256, 0, stream>>>(xpH, cbTh, negC0, pkey);
    k_rescore<<<NN / 4, 256, 0, stream>>>(xp, cbT, pkey, idxv, outIdx, pmin);
    k_gather<<<NN / 32 + 1, 256, 0, stream>>>(cbT, idxv, pmin, out0, outDiff);
}

// Round 16
// 242.380 us; speedup vs baseline: 1.9942x; 1.0773x over previous
//
#include <hip/hip_runtime.h>

typedef short bf16x8 __attribute__((ext_vector_type(8)));
typedef float f32x4 __attribute__((ext_vector_type(4)));
typedef float f32x16 __attribute__((ext_vector_type(16)));
using u16 = unsigned short;
using u32 = unsigned int;

#define MFMA_BF16(A, B, C) __builtin_amdgcn_mfma_f32_16x16x32_bf16((A), (B), (C), 0, 0, 0)
#define MFMA32_BF16(A, B, C) __builtin_amdgcn_mfma_f32_32x32x16_bf16((A), (B), (C), 0, 0, 0)

#define CC 256
#define DD 256
#define KK 8192
#define NN 16384     // B*H*W
#define HW 1024      // H*W
#define OUT0 4194304 // B*D*H*W
#define KSPLIT 16
#define KROWS 32     // k-rows (codes) per LDS tile (verified best)

static __device__ __forceinline__ float b2f(u16 u) {
    union { u32 i; float f; } v; v.i = ((u32)u) << 16; return v.f;
}
static __device__ __forceinline__ u16 f2b(float f) {  // RNE fp32 -> bf16
    union { float f; u32 i; } v; v.f = f;
    u32 x = v.i;
    u32 r = (x + 0x7fffu + ((x >> 16) & 1u)) >> 16;
    return (u16)r;
}
static __device__ __forceinline__ u32 f2u(float f) {
    union { float f; u32 u; } v; v.f = f; return v.u;
}
static __device__ __forceinline__ void split3(float v, u16& h, u16& m, u16& l) {
    h = f2b(v); float r1 = v - b2f(h);
    m = f2b(r1); float r2 = r1 - b2f(m);
    l = f2b(r2);
}

typedef __attribute__((address_space(1))) const u32 GlbU32;
typedef __attribute__((address_space(3))) u32 LdsU32;
static __device__ __forceinline__ void async_load16(const void* g, void* l) {
    __builtin_amdgcn_global_load_lds((GlbU32*)g, (LdsU32*)l, 16, 0, 0);
}

// ---------------------------------------------------------------------------
// K0 (fused prep): blocks [0,2048): transpose cb -> cbT fp32 + cbTh bf16;
// blocks [2048,2304): negC0[k] = -0.5*(||c_k||^2 + 1024);
// blocks [2304,2560): 3-way bf16 split of conv_w into FRAGMENT-PACKED layout
// (R16): wpack index t = ((dtg*8+cc)*64 + lane)*8 + j holds
// W[dtg*16+(lane&15)][cc*32+(lane>>4)*8+j] — k_proj's per-instruction W read
// becomes one contiguous 1 KB wave burst (was 64 x 16 B scattered requests).
__global__ __launch_bounds__(256) void k_prep(const float* __restrict__ cb,
                                              const float* __restrict__ Wm,
                                              float* __restrict__ cbT,
                                              u16* __restrict__ cbTh,
                                              float* __restrict__ negC0,
                                              u16* __restrict__ wh,
                                              u16* __restrict__ wm,
                                              u16* __restrict__ wl) {
    int bx = blockIdx.x, tid = threadIdx.x;
    if (bx < 2048) {
        __shared__ float tile[32][33];
        int k0 = (bx & 255) * 32, d0 = (bx >> 8) * 32;
        int tx = tid & 31, ty = tid >> 5;  // 32 x 8
#pragma unroll
        for (int i = 0; i < 4; i++) {
            int d = d0 + ty + i * 8;
            tile[ty + i * 8][tx] = cb[d * KK + k0 + tx];
        }
        __syncthreads();
#pragma unroll
        for (int i = 0; i < 4; i++) {
            int k = k0 + ty + i * 8;
            float v = tile[tx][ty + i * 8];
            cbT[k * DD + d0 + tx] = v;
            cbTh[k * DD + d0 + tx] = f2b(v);
        }
    } else if (bx < 2304) {
        __shared__ float sm[8][32];
        int kl = tid & 31, dg = tid >> 5;
        int k = (bx - 2048) * 32 + kl;
        float s = 0.f;
#pragma unroll
        for (int j = 0; j < 32; j++) {
            float v = cb[(size_t)(dg * 32 + j) * KK + k];
            s += v * v;
        }
        sm[dg][kl] = s;
        __syncthreads();
        if (tid < 32) {
            float t = 0.f;
#pragma unroll
            for (int g = 0; g < 8; g++) t += sm[g][tid];
            negC0[(bx - 2048) * 32 + tid] = -0.5f * (t + 1024.f);
        }
    } else {
        int t = (bx - 2304) * 256 + tid;      // packed index
        int j    = t & 7;
        int lane = (t >> 3) & 63;
        int cc   = (t >> 9) & 7;
        int dtg  = t >> 12;
        int l15 = lane & 15, quad = lane >> 4;
        int src = (dtg * 16 + l15) * CC + cc * 32 + quad * 8 + j;
        u16 h, m, l; split3(Wm[src], h, m, l);
        wh[t] = h; wm[t] = m; wl[t] = l;
    }
}

// ---------------------------------------------------------------------------
// K1: xp = x_r @ W^T + b via bf16x3 split MFMA (6 terms ~ fp32 accuracy).
// R16: (1) W reads use the fragment-packed layout — off = ((dtg*8+cc)*64 +
// lane)*8, one contiguous 1 KB burst per instruction (was 64 scattered 16 B
// requests; same defect class as k_rescore's R15 +26 us fix). (2) dt-split
// x2: grid 2048 (bx>>1 = n-tile, bx&1 = d-half), wave = dt-pair, acc[2] ->
// 8 blocks/CU, up to 8 waves/SIMD (was 4). x re-read x2 is L2/L3-resident
// (R11: 9.8 MB HBM fetch only).
__global__ __launch_bounds__(256) void k_proj(const float* __restrict__ x,
                                              const u16* __restrict__ wh,
                                              const u16* __restrict__ wm,
                                              const u16* __restrict__ wl,
                                              const float* __restrict__ bias,
                                              float* __restrict__ xp,
                                              u16* __restrict__ xpH) {
    int tid = threadIdx.x;
    int wave = tid >> 6, lane = tid & 63;
    int quad = lane >> 4, l15 = lane & 15;
    int n0 = (blockIdx.x >> 1) * 16;
    int dhalf = blockIdx.x & 1;              // which 128-d half
    int n_a = n0 + l15;
    const float* xb = x + (n_a >> 10) * (CC * HW) + (n_a & (HW - 1));

    f32x4 acc[2];
#pragma unroll
    for (int i = 0; i < 2; i++) acc[i] = (f32x4){0.f, 0.f, 0.f, 0.f};

#pragma unroll
    for (int cc = 0; cc < 8; cc++) {
        bf16x8 ah, am, al;
#pragma unroll
        for (int j = 0; j < 8; j++) {
            float v = xb[(cc * 32 + quad * 8 + j) * HW];
            u16 h, m, l; split3(v, h, m, l);
            ah[j] = (short)h; am[j] = (short)m; al[j] = (short)l;
        }
#pragma unroll
        for (int dt = 0; dt < 2; dt++) {
            int dtg = dhalf * 8 + wave * 2 + dt;
            int off = ((dtg * 8 + cc) * 64 + lane) * 8;   // packed: 1 KB/wave burst
            const bf16x8 bh = *(const bf16x8*)(wh + off);
            const bf16x8 bm = *(const bf16x8*)(wm + off);
            const bf16x8 bl = *(const bf16x8*)(wl + off);
            acc[dt] = MFMA_BF16(ah, bh, acc[dt]);
            acc[dt] = MFMA_BF16(am, bh, acc[dt]);
            acc[dt] = MFMA_BF16(ah, bm, acc[dt]);
            acc[dt] = MFMA_BF16(al, bh, acc[dt]);
            acc[dt] = MFMA_BF16(am, bm, acc[dt]);
            acc[dt] = MFMA_BF16(ah, bl, acc[dt]);
        }
    }

#pragma unroll
    for (int dt = 0; dt < 2; dt++) {
        int dtg = dhalf * 8 + wave * 2 + dt;
        int d = dtg * 16 + l15;              // C-layout: col = lane&15
        float bv = bias[d];
#pragma unroll
        for (int r = 0; r < 4; r++) {
            int n = n0 + quad * 4 + r;       // C-layout: row = quad*4 + reg
            float v = acc[dt][r] + bv;
            xp[n * DD + d] = v;
            xpH[n * DD + d] = f2b(v);
        }
    }
}

// ---------------------------------------------------------------------------
// K2: approx distance GEMM (32x32x16 MFMA) + fused argmin-candidate select.
// Verified best structure: KROWS=32, XOR swizzle, 512-u16 chunk stride,
// 2 LDS buffers, __syncthreads per kc, mt=1, ILP-2 MFMA chains. 8 structural
// experiments all regressed — measured local optimum.
// C/D (verified m74/m101): col = lane&31, row = (reg&3)+8*(reg>>2)+4*(lane>>5).
__global__ __launch_bounds__(256, 3) void k_dist(const u16* __restrict__ xpH,
                                                 const u16* __restrict__ cbTh,
                                                 const float* __restrict__ negC0,
                                                 u32* __restrict__ pkey) {
    __shared__ __align__(16) u16 tile[2][KROWS * 256];  // 2 x 16 KB
    int tid = threadIdx.x, wave = tid >> 6, lane = tid & 63;
    int col = lane & 31, half = lane >> 5;
    int n0 = blockIdx.x * 128 + wave * 32;
    int ksbase = blockIdx.y * (KK / KSPLIT);   // 512 codes per split

    // A-frags resident: 16 ks (row = col, dims ks*16 + half*8 + j)
    bf16x8 Ah[16];
    {
        const u16* ab = xpH + (size_t)(n0 + col) * DD + half * 8;
#pragma unroll
        for (int ks = 0; ks < 16; ks++)
            Ah[ks] = *(const bf16x8*)(ab + ks * 16);
    }

    u32 key[16];
#pragma unroll
    for (int g = 0; g < 16; g++) key[g] = 0xffffffffu;

#define STAGE(bufi, kglob_)                                                    \
    {                                                                          \
        int kg_ = (kglob_);                                                    \
        _Pragma("unroll")                                                      \
        for (int c = 0; c < 4; c++) {                                          \
            int chunk = wave * 4 + c;                                          \
            int row = chunk * 2 + (lane >> 5);                                 \
            int g = (lane & 31) ^ (row & 7);                                   \
            const u16* src = cbTh + (size_t)(kg_ + row) * DD + g * 8;          \
            async_load16(src, &tile[bufi][chunk * 512]);                       \
        }                                                                      \
    }

    STAGE(0, ksbase);
    float nc_cur = negC0[ksbase + col];
    __syncthreads();

    for (int kc = 0; kc < 16; kc++) {
        int buf = kc & 1;
        float nc_next = 0.f;
        if (kc < 15) {
            STAGE(buf ^ 1, ksbase + (kc + 1) * KROWS);
            nc_next = negC0[ksbase + (kc + 1) * KROWS + col];
        }

        f32x16 a0, a1;
#pragma unroll
        for (int g = 0; g < 16; g++) { a0[g] = nc_cur; a1[g] = 0.f; }

        const u16* trow = &tile[buf][col * 256];
#pragma unroll
        for (int ks = 0; ks < 8; ks++) {
            int g0 = ((2 * ks) * 2 + half) ^ (col & 7);
            int g1 = ((2 * ks + 1) * 2 + half) ^ (col & 7);
            const bf16x8 Bf0 = *(const bf16x8*)(trow + g0 * 8);
            const bf16x8 Bf1 = *(const bf16x8*)(trow + g1 * 8);
            a0 = MFMA32_BF16(Ah[2 * ks], Bf0, a0);
            a1 = MFMA32_BF16(Ah[2 * ks + 1], Bf1, a1);
        }

        u32 orv = ((u32)kc << 5) | (u32)col;
#pragma unroll
        for (int g = 0; g < 16; g++) {
            u32 kb = (f2u(a0[g] + a1[g]) & 0xFFFFFE00u) | orv;
            key[g] = min(key[g], kb);
        }
        nc_cur = nc_next;
        __syncthreads();  // drains prefetch + guards buffers
    }
#undef STAGE

    // top-2 across the 32 lanes (cols) sharing each C row
#pragma unroll
    for (int g = 0; g < 16; g++) {
        u32 k1 = key[g], k2 = 0xffffffffu;
#pragma unroll
        for (int m = 1; m < 32; m <<= 1) {
            u32 o1 = (u32)__shfl_xor((int)k1, m, 64);
            u32 o2 = (u32)__shfl_xor((int)k2, m, 64);
            u32 mx = max(k1, o1);
            k1 = min(k1, o1);
            k2 = min(min(k2, o2), mx);
        }
        if (col == 0) {
            int row = (g & 3) + 8 * (g >> 2) + 4 * half;
            int n = n0 + row;
            int base = (n * KSPLIT + blockIdx.y) * 2;
            pkey[base]     = (u32)ksbase + (k1 & 511u);
            pkey[base + 1] = (u32)ksbase + (k2 & 511u);
        }
    }
}

// ---------------------------------------------------------------------------
// K3: exact fp64 rescore of 32 candidates per row. One wave per row, 4 serial
// groups. R15 coalescing fix (contiguous 128 B per instruction per row)
// verified: -26 us. Lane->element partition arbitrary for the distance sum.
__global__ __launch_bounds__(256) void k_rescore(const float* __restrict__ xp,
                                                 const float* __restrict__ cbT,
                                                 const u32* __restrict__ pkey,
                                                 u32* __restrict__ idxv,
                                                 float* __restrict__ outIdx,
                                                 float* __restrict__ pmin) {
    int tid = threadIdx.x, wave = tid >> 6, lane = tid & 63;
    int n = blockIdx.x * 4 + wave;
    int sub = lane >> 3;
    int oct = lane & 7;

    f32x4 xv[8];
    const float* xb = xp + n * DD;
#pragma unroll
    for (int t = 0; t < 8; t++) xv[t] = *(const f32x4*)(xb + (t * 8 + oct) * 4);

    u32 myk = pkey[n * 32 + (lane & 31)] & 8191u;

    double bestv = 1e300;
    u32 besti = 0u;
#pragma unroll
    for (int g = 0; g < 4; g++) {
        int c = g * 8 + sub;
        u32 kg = (u32)__shfl((int)myk, c, 64);
        const float* cv = cbT + (size_t)kg * DD;
        double s = 0.0;
#pragma unroll
        for (int t = 0; t < 8; t++) {
            f32x4 cvv = *(const f32x4*)(cv + (t * 8 + oct) * 4);
#pragma unroll
            for (int q = 0; q < 4; q++) {
                double d = (double)xv[t][q] - (double)cvv[q];
                s += d * d;
            }
        }
        s += __shfl_xor(s, 1, 64);
        s += __shfl_xor(s, 2, 64);
        s += __shfl_xor(s, 4, 64);
        if (s < bestv || (s == bestv && kg < besti)) { bestv = s; besti = kg; }
    }
#pragma unroll
    for (int m = 8; m < 64; m <<= 1) {
        double ov = __shfl_xor(bestv, m, 64);
        u32 oi = (u32)__shfl_xor((int)besti, m, 64);
        if (ov < bestv || (ov == bestv && oi < besti)) { bestv = ov; besti = oi; }
    }
    if (lane == 0) {
        idxv[n] = besti;
        outIdx[n] = (float)besti;
        pmin[n] = (float)bestv;
    }
}

// ---------------------------------------------------------------------------
// K5 (k_final folded in): gather quantized (B,D,H,W) fp32 via LDS transpose
// tiles; block NN/32 reduces pmin -> outDiff. Coalesced cbT staging reads.
// Rewrites ALL of d_out chunk 0.
__global__ __launch_bounds__(256) void k_gather(const float* __restrict__ cbT,
                                                const u32* __restrict__ idxv,
                                                const float* __restrict__ pmin,
                                                float* __restrict__ out0,
                                                float* __restrict__ outDiff) {
    if (blockIdx.x == NN / 32) {
        // fused k_final: diff = sum(pmin)/(N*D), fp64. 256 threads x 64 vals.
        __shared__ double sm[4];
        int tid = threadIdx.x, lane = tid & 63, wv = tid >> 6;
        double s = 0.0;
#pragma unroll
        for (int i = 0; i < 64; i++) s += (double)pmin[i * 256 + tid];
#pragma unroll
        for (int m = 1; m < 64; m <<= 1) s += __shfl_xor(s, m, 64);
        if (lane == 0) sm[wv] = s;
        __syncthreads();
        if (tid == 0)
            outDiff[0] = (float)((sm[0] + sm[1] + sm[2] + sm[3]) * (1.0 / (double)OUT0));
        return;
    }

    __shared__ float tile[32 * 260];
    int tid = threadIdx.x;
    int n0 = blockIdx.x * 32;
    int b = n0 >> 10, hw0 = n0 & 1023;

    {
        int r = tid >> 3, seg = tid & 7;
        u32 k = idxv[n0 + r] & 8191u;
        const float* src = cbT + (size_t)k * DD;
        float* dst = tile + r * 260;
#pragma unroll
        for (int j = 0; j < 8; j++)
            *(f32x4*)(dst + (j * 8 + seg) * 4) = *(const f32x4*)(src + (j * 8 + seg) * 4);
    }
    __syncthreads();
    {
        int hw = tid & 31, dq = tid >> 5;
        const float* trow = tile + hw * 260;
        float* obase = out0 + ((size_t)b * DD) * HW + hw0 + hw;
#pragma unroll
        for (int dj = 0; dj < 32; dj++) {
            int d = dq * 32 + dj;
            obase[(size_t)d * HW] = trow[d];
        }
    }
}

// ---------------------------------------------------------------------------
extern "C" void kernel_launch(void* const* d_in, const int* in_sizes, int n_in,
                              void* d_out, int out_size, void* d_ws, size_t ws_size,
                              hipStream_t stream) {
    const float* x = nullptr; const float* Wm = nullptr;
    const float* bias = nullptr; const float* cb = nullptr;
    for (int i = 0; i < n_in; i++) {
        switch (in_sizes[i]) {
            case 4194304: x    = (const float*)d_in[i]; break;  // (16,256,32,32)
            case 65536:   Wm   = (const float*)d_in[i]; break;  // (256,256)
            case 256:     bias = (const float*)d_in[i]; break;  // (256,)
            case 2097152: cb   = (const float*)d_in[i]; break;  // (256,8192)
        }
    }

    // d_out is FP32: [quantized (4194304) | diff (1) | indices (16384)]
    float* out0    = (float*)d_out;
    float* outDiff = (float*)d_out + OUT0;
    float* outIdx  = (float*)d_out + OUT0 + 1;

    // Transient scratch inside d_out chunk 0 (16.78 MB; every byte rewritten
    // by k_gather before the harness reads):
    char* o = (char*)d_out;
    u16*   cbTh = (u16*)o;                       // [0, 4 MB)
    u32*   pkey = (u32*)(o + 4194304);           // [4 MB, 6 MB)
    u16*   wh   = (u16*)(o + 6291456);           // 128 KB
    u16*   wm   = (u16*)(o + 6422528);           // 128 KB
    u16*   wl   = (u16*)(o + 6553600);           // 128 KB
    u16*   xpH  = (u16*)(o + 6750208);           // 8 MB  (N,D) bf16 -> ends 14.75 MB

    // Workspace (~25.33 MB, footprint that passed in rounds 4-9):
    char* w = (char*)d_ws;
    float* cbT   = (float*)(w);                  // 8 MB  (K,D) fp32
    float* xp    = (float*)(w + 8388608);        // 16 MB (N,D) fp32
    float* negC0 = (float*)(w + 25165824);       // 32 KB
    u32*   idxv  = (u32*)(w + 25198592);         // 64 KB
    float* pmin  = (float*)(w + 25264128);       // 64 KB

    k_prep<<<2560, 256, 0, stream>>>(cb, Wm, cbT, cbTh, negC0, wh, wm, wl);
    k_proj<<<NN / 8, 256, 0, stream>>>(x, wh, wm, wl, bias, xp, xpH);
    k_dist<<<dim3(NN / 128, KSPLIT), 256, 0, stream>>>(xpH, cbTh, negC0, pkey);
    k_rescore<<<NN / 4, 256, 0, stream>>>(xp, cbT, pkey, idxv, outIdx, pmin);
    k_gather<<<NN / 32 + 1, 256, 0, stream>>>(cbT, idxv, pmin, out0, outDiff);
}

// Round 17
// 235.331 us; speedup vs baseline: 2.0539x; 1.0300x over previous
//
#include <hip/hip_runtime.h>

typedef short bf16x8 __attribute__((ext_vector_type(8)));
typedef float f32x4 __attribute__((ext_vector_type(4)));
typedef float f32x16 __attribute__((ext_vector_type(16)));
using u16 = unsigned short;
using u32 = unsigned int;

#define MFMA_BF16(A, B, C) __builtin_amdgcn_mfma_f32_16x16x32_bf16((A), (B), (C), 0, 0, 0)
#define MFMA32_BF16(A, B, C) __builtin_amdgcn_mfma_f32_32x32x16_bf16((A), (B), (C), 0, 0, 0)

#define CC 256
#define DD 256
#define KK 8192
#define NN 16384     // B*H*W
#define HW 1024      // H*W
#define OUT0 4194304 // B*D*H*W
#define KSPLIT 16
#define KROWS 32     // k-rows (codes) per LDS tile (verified best)

static __device__ __forceinline__ float b2f(u16 u) {
    union { u32 i; float f; } v; v.i = ((u32)u) << 16; return v.f;
}
static __device__ __forceinline__ u16 f2b(float f) {  // RNE fp32 -> bf16
    union { float f; u32 i; } v; v.f = f;
    u32 x = v.i;
    u32 r = (x + 0x7fffu + ((x >> 16) & 1u)) >> 16;
    return (u16)r;
}
static __device__ __forceinline__ u32 f2u(float f) {
    union { float f; u32 u; } v; v.f = f; return v.u;
}
static __device__ __forceinline__ void split3(float v, u16& h, u16& m, u16& l) {
    h = f2b(v); float r1 = v - b2f(h);
    m = f2b(r1); float r2 = r1 - b2f(m);
    l = f2b(r2);
}

typedef __attribute__((address_space(1))) const u32 GlbU32;
typedef __attribute__((address_space(3))) u32 LdsU32;
static __device__ __forceinline__ void async_load16(const void* g, void* l) {
    __builtin_amdgcn_global_load_lds((GlbU32*)g, (LdsU32*)l, 16, 0, 0);
}

// ---------------------------------------------------------------------------
// K0 (fused prep): blocks [0,2048): transpose cb -> cbT fp32 + cbTh bf16;
// blocks [2048,2304): negC0[k] = -0.5*(||c_k||^2 + 1024);
// blocks [2304,2560): 3-way bf16 split of conv_w into FRAGMENT-PACKED layout
// (R16): wpack index t = ((dtg*8+cc)*64 + lane)*8 + j holds
// W[dtg*16+(lane&15)][cc*32+(lane>>4)*8+j] — k_proj's per-instruction W read
// becomes one contiguous 1 KB wave burst (was 64 x 16 B scattered requests).
__global__ __launch_bounds__(256) void k_prep(const float* __restrict__ cb,
                                              const float* __restrict__ Wm,
                                              float* __restrict__ cbT,
                                              u16* __restrict__ cbTh,
                                              float* __restrict__ negC0,
                                              u16* __restrict__ wh,
                                              u16* __restrict__ wm,
                                              u16* __restrict__ wl) {
    int bx = blockIdx.x, tid = threadIdx.x;
    if (bx < 2048) {
        __shared__ float tile[32][33];
        int k0 = (bx & 255) * 32, d0 = (bx >> 8) * 32;
        int tx = tid & 31, ty = tid >> 5;  // 32 x 8
#pragma unroll
        for (int i = 0; i < 4; i++) {
            int d = d0 + ty + i * 8;
            tile[ty + i * 8][tx] = cb[d * KK + k0 + tx];
        }
        __syncthreads();
#pragma unroll
        for (int i = 0; i < 4; i++) {
            int k = k0 + ty + i * 8;
            float v = tile[tx][ty + i * 8];
            cbT[k * DD + d0 + tx] = v;
            cbTh[k * DD + d0 + tx] = f2b(v);
        }
    } else if (bx < 2304) {
        __shared__ float sm[8][32];
        int kl = tid & 31, dg = tid >> 5;
        int k = (bx - 2048) * 32 + kl;
        float s = 0.f;
#pragma unroll
        for (int j = 0; j < 32; j++) {
            float v = cb[(size_t)(dg * 32 + j) * KK + k];
            s += v * v;
        }
        sm[dg][kl] = s;
        __syncthreads();
        if (tid < 32) {
            float t = 0.f;
#pragma unroll
            for (int g = 0; g < 8; g++) t += sm[g][tid];
            negC0[(bx - 2048) * 32 + tid] = -0.5f * (t + 1024.f);
        }
    } else {
        int t = (bx - 2304) * 256 + tid;      // packed index
        int j    = t & 7;
        int lane = (t >> 3) & 63;
        int cc   = (t >> 9) & 7;
        int dtg  = t >> 12;
        int l15 = lane & 15, quad = lane >> 4;
        int src = (dtg * 16 + l15) * CC + cc * 32 + quad * 8 + j;
        u16 h, m, l; split3(Wm[src], h, m, l);
        wh[t] = h; wm[t] = m; wl[t] = l;
    }
}

// ---------------------------------------------------------------------------
// K1: xp = x_r @ W^T + b via bf16x3 split MFMA (6 terms ~ fp32 accuracy).
// R16 structure (verified: proj ~46 -> ~27 us): fragment-packed W reads
// (1 KB burst/instruction) + dt-split x2 (grid 2048, 8 blocks/CU).
__global__ __launch_bounds__(256) void k_proj(const float* __restrict__ x,
                                              const u16* __restrict__ wh,
                                              const u16* __restrict__ wm,
                                              const u16* __restrict__ wl,
                                              const float* __restrict__ bias,
                                              float* __restrict__ xp,
                                              u16* __restrict__ xpH) {
    int tid = threadIdx.x;
    int wave = tid >> 6, lane = tid & 63;
    int quad = lane >> 4, l15 = lane & 15;
    int n0 = (blockIdx.x >> 1) * 16;
    int dhalf = blockIdx.x & 1;              // which 128-d half
    int n_a = n0 + l15;
    const float* xb = x + (n_a >> 10) * (CC * HW) + (n_a & (HW - 1));

    f32x4 acc[2];
#pragma unroll
    for (int i = 0; i < 2; i++) acc[i] = (f32x4){0.f, 0.f, 0.f, 0.f};

#pragma unroll
    for (int cc = 0; cc < 8; cc++) {
        bf16x8 ah, am, al;
#pragma unroll
        for (int j = 0; j < 8; j++) {
            float v = xb[(cc * 32 + quad * 8 + j) * HW];
            u16 h, m, l; split3(v, h, m, l);
            ah[j] = (short)h; am[j] = (short)m; al[j] = (short)l;
        }
#pragma unroll
        for (int dt = 0; dt < 2; dt++) {
            int dtg = dhalf * 8 + wave * 2 + dt;
            int off = ((dtg * 8 + cc) * 64 + lane) * 8;   // packed: 1 KB/wave burst
            const bf16x8 bh = *(const bf16x8*)(wh + off);
            const bf16x8 bm = *(const bf16x8*)(wm + off);
            const bf16x8 bl = *(const bf16x8*)(wl + off);
            acc[dt] = MFMA_BF16(ah, bh, acc[dt]);
            acc[dt] = MFMA_BF16(am, bh, acc[dt]);
            acc[dt] = MFMA_BF16(ah, bm, acc[dt]);
            acc[dt] = MFMA_BF16(al, bh, acc[dt]);
            acc[dt] = MFMA_BF16(am, bm, acc[dt]);
            acc[dt] = MFMA_BF16(ah, bl, acc[dt]);
        }
    }

#pragma unroll
    for (int dt = 0; dt < 2; dt++) {
        int dtg = dhalf * 8 + wave * 2 + dt;
        int d = dtg * 16 + l15;              // C-layout: col = lane&15
        float bv = bias[d];
#pragma unroll
        for (int r = 0; r < 4; r++) {
            int n = n0 + quad * 4 + r;       // C-layout: row = quad*4 + reg
            float v = acc[dt][r] + bv;
            xp[n * DD + d] = v;
            xpH[n * DD + d] = f2b(v);
        }
    }
}

// ---------------------------------------------------------------------------
// K2: approx distance GEMM (32x32x16 MFMA) + fused argmin-candidate select.
// Verified best structure: KROWS=32, XOR swizzle, 512-u16 chunk stride,
// 2 LDS buffers, __syncthreads per kc, mt=1, ILP-2 MFMA chains. 8 structural
// experiments all regressed — measured local optimum.
// C/D (verified m74/m101): col = lane&31, row = (reg&3)+8*(reg>>2)+4*(lane>>5).
__global__ __launch_bounds__(256, 3) void k_dist(const u16* __restrict__ xpH,
                                                 const u16* __restrict__ cbTh,
                                                 const float* __restrict__ negC0,
                                                 u32* __restrict__ pkey) {
    __shared__ __align__(16) u16 tile[2][KROWS * 256];  // 2 x 16 KB
    int tid = threadIdx.x, wave = tid >> 6, lane = tid & 63;
    int col = lane & 31, half = lane >> 5;
    int n0 = blockIdx.x * 128 + wave * 32;
    int ksbase = blockIdx.y * (KK / KSPLIT);   // 512 codes per split

    // A-frags resident: 16 ks (row = col, dims ks*16 + half*8 + j)
    bf16x8 Ah[16];
    {
        const u16* ab = xpH + (size_t)(n0 + col) * DD + half * 8;
#pragma unroll
        for (int ks = 0; ks < 16; ks++)
            Ah[ks] = *(const bf16x8*)(ab + ks * 16);
    }

    u32 key[16];
#pragma unroll
    for (int g = 0; g < 16; g++) key[g] = 0xffffffffu;

#define STAGE(bufi, kglob_)                                                    \
    {                                                                          \
        int kg_ = (kglob_);                                                    \
        _Pragma("unroll")                                                      \
        for (int c = 0; c < 4; c++) {                                          \
            int chunk = wave * 4 + c;                                          \
            int row = chunk * 2 + (lane >> 5);                                 \
            int g = (lane & 31) ^ (row & 7);                                   \
            const u16* src = cbTh + (size_t)(kg_ + row) * DD + g * 8;          \
            async_load16(src, &tile[bufi][chunk * 512]);                       \
        }                                                                      \
    }

    STAGE(0, ksbase);
    float nc_cur = negC0[ksbase + col];
    __syncthreads();

    for (int kc = 0; kc < 16; kc++) {
        int buf = kc & 1;
        float nc_next = 0.f;
        if (kc < 15) {
            STAGE(buf ^ 1, ksbase + (kc + 1) * KROWS);
            nc_next = negC0[ksbase + (kc + 1) * KROWS + col];
        }

        f32x16 a0, a1;
#pragma unroll
        for (int g = 0; g < 16; g++) { a0[g] = nc_cur; a1[g] = 0.f; }

        const u16* trow = &tile[buf][col * 256];
#pragma unroll
        for (int ks = 0; ks < 8; ks++) {
            int g0 = ((2 * ks) * 2 + half) ^ (col & 7);
            int g1 = ((2 * ks + 1) * 2 + half) ^ (col & 7);
            const bf16x8 Bf0 = *(const bf16x8*)(trow + g0 * 8);
            const bf16x8 Bf1 = *(const bf16x8*)(trow + g1 * 8);
            a0 = MFMA32_BF16(Ah[2 * ks], Bf0, a0);
            a1 = MFMA32_BF16(Ah[2 * ks + 1], Bf1, a1);
        }

        u32 orv = ((u32)kc << 5) | (u32)col;
#pragma unroll
        for (int g = 0; g < 16; g++) {
            u32 kb = (f2u(a0[g] + a1[g]) & 0xFFFFFE00u) | orv;
            key[g] = min(key[g], kb);
        }
        nc_cur = nc_next;
        __syncthreads();  // drains prefetch + guards buffers
    }
#undef STAGE

    // top-2 across the 32 lanes (cols) sharing each C row
#pragma unroll
    for (int g = 0; g < 16; g++) {
        u32 k1 = key[g], k2 = 0xffffffffu;
#pragma unroll
        for (int m = 1; m < 32; m <<= 1) {
            u32 o1 = (u32)__shfl_xor((int)k1, m, 64);
            u32 o2 = (u32)__shfl_xor((int)k2, m, 64);
            u32 mx = max(k1, o1);
            k1 = min(k1, o1);
            k2 = min(min(k2, o2), mx);
        }
        if (col == 0) {
            int row = (g & 3) + 8 * (g >> 2) + 4 * half;
            int n = n0 + row;
            int base = (n * KSPLIT + blockIdx.y) * 2;
            pkey[base]     = (u32)ksbase + (k1 & 511u);
            pkey[base + 1] = (u32)ksbase + (k2 & 511u);
        }
    }
}

// ---------------------------------------------------------------------------
// K3: exact fp64 rescore of 32 candidates per row.
// R17: TLP (R10 structure) x coalesced reads (R15 indexing). ONE BLOCK
// (4 waves) per row, one candidate-group per wave: the 4 gather rounds that
// were serial within one wave now run CONCURRENTLY in 4 waves — 4x the
// in-flight L3 gathers. R10 failed pre-coalescing (request-saturated); R15
// cut requests 8x, leaving ~600-700 cyc L3 latency as the wall (R9/R15:
// VALUBusy ~18%, nothing saturated) — TLP is now the right lever.
// Comparator is a lexicographic (value, index) min — total order, so the
// reduction-order change is result-identical.
__global__ __launch_bounds__(256) void k_rescore(const float* __restrict__ xp,
                                                 const float* __restrict__ cbT,
                                                 const u32* __restrict__ pkey,
                                                 u32* __restrict__ idxv,
                                                 float* __restrict__ outIdx,
                                                 float* __restrict__ pmin) {
    __shared__ double sbv[4];
    __shared__ u32 sbi[4];
    int tid = threadIdx.x, wave = tid >> 6, lane = tid & 63;
    int n = blockIdx.x;
    int sub = lane >> 3;
    int oct = lane & 7;

    f32x4 xv[8];
    const float* xb = xp + n * DD;
#pragma unroll
    for (int t = 0; t < 8; t++) xv[t] = *(const f32x4*)(xb + (t * 8 + oct) * 4);

    // this wave's candidate for this sub-group (8 lanes share one candidate)
    u32 kg = pkey[n * 32 + wave * 8 + sub] & 8191u;

    const float* cv = cbT + (size_t)kg * DD;
    double s = 0.0;
#pragma unroll
    for (int t = 0; t < 8; t++) {
        f32x4 cvv = *(const f32x4*)(cv + (t * 8 + oct) * 4);
#pragma unroll
        for (int q = 0; q < 4; q++) {
            double d = (double)xv[t][q] - (double)cvv[q];
            s += d * d;
        }
    }
    s += __shfl_xor(s, 1, 64);
    s += __shfl_xor(s, 2, 64);
    s += __shfl_xor(s, 4, 64);

    double bestv = s;
    u32 besti = kg;
#pragma unroll
    for (int m = 8; m < 64; m <<= 1) {
        double ov = __shfl_xor(bestv, m, 64);
        u32 oi = (u32)__shfl_xor((int)besti, m, 64);
        if (ov < bestv || (ov == bestv && oi < besti)) { bestv = ov; besti = oi; }
    }
    if (lane == 0) { sbv[wave] = bestv; sbi[wave] = besti; }
    __syncthreads();
    if (tid == 0) {
        double bv = sbv[0]; u32 bi = sbi[0];
#pragma unroll
        for (int wv = 1; wv < 4; wv++) {
            double ov = sbv[wv]; u32 oi = sbi[wv];
            if (ov < bv || (ov == bv && oi < bi)) { bv = ov; bi = oi; }
        }
        idxv[n] = bi;
        outIdx[n] = (float)bi;
        pmin[n] = (float)bv;
    }
}

// ---------------------------------------------------------------------------
// K5 (k_final folded in): gather quantized (B,D,H,W) fp32 via LDS transpose
// tiles; block NN/32 reduces pmin -> outDiff. Coalesced cbT staging reads.
// Rewrites ALL of d_out chunk 0.
__global__ __launch_bounds__(256) void k_gather(const float* __restrict__ cbT,
                                                const u32* __restrict__ idxv,
                                                const float* __restrict__ pmin,
                                                float* __restrict__ out0,
                                                float* __restrict__ outDiff) {
    if (blockIdx.x == NN / 32) {
        // fused k_final: diff = sum(pmin)/(N*D), fp64. 256 threads x 64 vals.
        __shared__ double sm[4];
        int tid = threadIdx.x, lane = tid & 63, wv = tid >> 6;
        double s = 0.0;
#pragma unroll
        for (int i = 0; i < 64; i++) s += (double)pmin[i * 256 + tid];
#pragma unroll
        for (int m = 1; m < 64; m <<= 1) s += __shfl_xor(s, m, 64);
        if (lane == 0) sm[wv] = s;
        __syncthreads();
        if (tid == 0)
            outDiff[0] = (float)((sm[0] + sm[1] + sm[2] + sm[3]) * (1.0 / (double)OUT0));
        return;
    }

    __shared__ float tile[32 * 260];
    int tid = threadIdx.x;
    int n0 = blockIdx.x * 32;
    int b = n0 >> 10, hw0 = n0 & 1023;

    {
        int r = tid >> 3, seg = tid & 7;
        u32 k = idxv[n0 + r] & 8191u;
        const float* src = cbT + (size_t)k * DD;
        float* dst = tile + r * 260;
#pragma unroll
        for (int j = 0; j < 8; j++)
            *(f32x4*)(dst + (j * 8 + seg) * 4) = *(const f32x4*)(src + (j * 8 + seg) * 4);
    }
    __syncthreads();
    {
        int hw = tid & 31, dq = tid >> 5;
        const float* trow = tile + hw * 260;
        float* obase = out0 + ((size_t)b * DD) * HW + hw0 + hw;
#pragma unroll
        for (int dj = 0; dj < 32; dj++) {
            int d = dq * 32 + dj;
            obase[(size_t)d * HW] = trow[d];
        }
    }
}

// ---------------------------------------------------------------------------
extern "C" void kernel_launch(void* const* d_in, const int* in_sizes, int n_in,
                              void* d_out, int out_size, void* d_ws, size_t ws_size,
                              hipStream_t stream) {
    const float* x = nullptr; const float* Wm = nullptr;
    const float* bias = nullptr; const float* cb = nullptr;
    for (int i = 0; i < n_in; i++) {
        switch (in_sizes[i]) {
            case 4194304: x    = (const float*)d_in[i]; break;  // (16,256,32,32)
            case 65536:   Wm   = (const float*)d_in[i]; break;  // (256,256)
            case 256:     bias = (const float*)d_in[i]; break;  // (256,)
            case 2097152: cb   = (const float*)d_in[i]; break;  // (256,8192)
        }
    }

    // d_out is FP32: [quantized (4194304) | diff (1) | indices (16384)]
    float* out0    = (float*)d_out;
    float* outDiff = (float*)d_out + OUT0;
    float* outIdx  = (float*)d_out + OUT0 + 1;

    // Transient scratch inside d_out chunk 0 (16.78 MB; every byte rewritten
    // by k_gather before the harness reads):
    char* o = (char*)d_out;
    u16*   cbTh = (u16*)o;                       // [0, 4 MB)
    u32*   pkey = (u32*)(o + 4194304);           // [4 MB, 6 MB)
    u16*   wh   = (u16*)(o + 6291456);           // 128 KB
    u16*   wm   = (u16*)(o + 6422528);           // 128 KB
    u16*   wl   = (u16*)(o + 6553600);           // 128 KB
    u16*   xpH  = (u16*)(o + 6750208);           // 8 MB  (N,D) bf16 -> ends 14.75 MB

    // Workspace (~25.33 MB, footprint that passed in rounds 4-9):
    char* w = (char*)d_ws;
    float* cbT   = (float*)(w);                  // 8 MB  (K,D) fp32
    float* xp    = (float*)(w + 8388608);        // 16 MB (N,D) fp32
    float* negC0 = (float*)(w + 25165824);       // 32 KB
    u32*   idxv  = (u32*)(w + 25198592);         // 64 KB
    float* pmin  = (float*)(w + 25264128);       // 64 KB

    k_prep<<<2560, 256, 0, stream>>>(cb, Wm, cbT, cbTh, negC0, wh, wm, wl);
    k_proj<<<NN / 8, 256, 0, stream>>>(x, wh, wm, wl, bias, xp, xpH);
    k_dist<<<dim3(NN / 128, KSPLIT), 256, 0, stream>>>(xpH, cbTh, negC0, pkey);
    k_rescore<<<NN, 256, 0, stream>>>(xp, cbT, pkey, idxv, outIdx, pmin);
    k_gather<<<NN / 32 + 1, 256, 0, stream>>>(cbT, idxv, pmin, out0, outDiff);
}

// Round 18
// 211.718 us; speedup vs baseline: 2.2830x; 1.1115x over previous
//
#include <hip/hip_runtime.h>

typedef short bf16x8 __attribute__((ext_vector_type(8)));
typedef float f32x4 __attribute__((ext_vector_type(4)));
typedef float f32x16 __attribute__((ext_vector_type(16)));
using u16 = unsigned short;
using u32 = unsigned int;

#define MFMA_BF16(A, B, C) __builtin_amdgcn_mfma_f32_16x16x32_bf16((A), (B), (C), 0, 0, 0)
#define MFMA32_BF16(A, B, C) __builtin_amdgcn_mfma_f32_32x32x16_bf16((A), (B), (C), 0, 0, 0)

#define CC 256
#define DD 256
#define KK 8192
#define NN 16384     // B*H*W
#define HW 1024      // H*W
#define OUT0 4194304 // B*D*H*W
#define KSPLIT 8     // R18: 16 -> 8 (1024-code splits; halves rescore bytes)
#define KROWS 32     // k-rows (codes) per LDS tile (verified best)

static __device__ __forceinline__ float b2f(u16 u) {
    union { u32 i; float f; } v; v.i = ((u32)u) << 16; return v.f;
}
static __device__ __forceinline__ u16 f2b(float f) {  // RNE fp32 -> bf16
    union { float f; u32 i; } v; v.f = f;
    u32 x = v.i;
    u32 r = (x + 0x7fffu + ((x >> 16) & 1u)) >> 16;
    return (u16)r;
}
static __device__ __forceinline__ u32 f2u(float f) {
    union { float f; u32 u; } v; v.f = f; return v.u;
}
static __device__ __forceinline__ void split3(float v, u16& h, u16& m, u16& l) {
    h = f2b(v); float r1 = v - b2f(h);
    m = f2b(r1); float r2 = r1 - b2f(m);
    l = f2b(r2);
}

typedef __attribute__((address_space(1))) const u32 GlbU32;
typedef __attribute__((address_space(3))) u32 LdsU32;
static __device__ __forceinline__ void async_load16(const void* g, void* l) {
    __builtin_amdgcn_global_load_lds((GlbU32*)g, (LdsU32*)l, 16, 0, 0);
}

// ---------------------------------------------------------------------------
// K0 (fused prep): blocks [0,2048): transpose cb -> cbT fp32 + cbTh bf16;
// blocks [2048,2304): negC0[k] = -0.5*(||c_k||^2 + 1024);
// blocks [2304,2560): 3-way bf16 split of conv_w into FRAGMENT-PACKED layout
// (R16): wpack index t = ((dtg*8+cc)*64 + lane)*8 + j.
__global__ __launch_bounds__(256) void k_prep(const float* __restrict__ cb,
                                              const float* __restrict__ Wm,
                                              float* __restrict__ cbT,
                                              u16* __restrict__ cbTh,
                                              float* __restrict__ negC0,
                                              u16* __restrict__ wh,
                                              u16* __restrict__ wm,
                                              u16* __restrict__ wl) {
    int bx = blockIdx.x, tid = threadIdx.x;
    if (bx < 2048) {
        __shared__ float tile[32][33];
        int k0 = (bx & 255) * 32, d0 = (bx >> 8) * 32;
        int tx = tid & 31, ty = tid >> 5;  // 32 x 8
#pragma unroll
        for (int i = 0; i < 4; i++) {
            int d = d0 + ty + i * 8;
            tile[ty + i * 8][tx] = cb[d * KK + k0 + tx];
        }
        __syncthreads();
#pragma unroll
        for (int i = 0; i < 4; i++) {
            int k = k0 + ty + i * 8;
            float v = tile[tx][ty + i * 8];
            cbT[k * DD + d0 + tx] = v;
            cbTh[k * DD + d0 + tx] = f2b(v);
        }
    } else if (bx < 2304) {
        __shared__ float sm[8][32];
        int kl = tid & 31, dg = tid >> 5;
        int k = (bx - 2048) * 32 + kl;
        float s = 0.f;
#pragma unroll
        for (int j = 0; j < 32; j++) {
            float v = cb[(size_t)(dg * 32 + j) * KK + k];
            s += v * v;
        }
        sm[dg][kl] = s;
        __syncthreads();
        if (tid < 32) {
            float t = 0.f;
#pragma unroll
            for (int g = 0; g < 8; g++) t += sm[g][tid];
            negC0[(bx - 2048) * 32 + tid] = -0.5f * (t + 1024.f);
        }
    } else {
        int t = (bx - 2304) * 256 + tid;      // packed index
        int j    = t & 7;
        int lane = (t >> 3) & 63;
        int cc   = (t >> 9) & 7;
        int dtg  = t >> 12;
        int l15 = lane & 15, quad = lane >> 4;
        int src = (dtg * 16 + l15) * CC + cc * 32 + quad * 8 + j;
        u16 h, m, l; split3(Wm[src], h, m, l);
        wh[t] = h; wm[t] = m; wl[t] = l;
    }
}

// ---------------------------------------------------------------------------
// K1: xp = x_r @ W^T + b via bf16x3 split MFMA (6 terms ~ fp32 accuracy).
// R16 structure (verified): fragment-packed W reads + dt-split x2.
__global__ __launch_bounds__(256) void k_proj(const float* __restrict__ x,
                                              const u16* __restrict__ wh,
                                              const u16* __restrict__ wm,
                                              const u16* __restrict__ wl,
                                              const float* __restrict__ bias,
                                              float* __restrict__ xp,
                                              u16* __restrict__ xpH) {
    int tid = threadIdx.x;
    int wave = tid >> 6, lane = tid & 63;
    int quad = lane >> 4, l15 = lane & 15;
    int n0 = (blockIdx.x >> 1) * 16;
    int dhalf = blockIdx.x & 1;              // which 128-d half
    int n_a = n0 + l15;
    const float* xb = x + (n_a >> 10) * (CC * HW) + (n_a & (HW - 1));

    f32x4 acc[2];
#pragma unroll
    for (int i = 0; i < 2; i++) acc[i] = (f32x4){0.f, 0.f, 0.f, 0.f};

#pragma unroll
    for (int cc = 0; cc < 8; cc++) {
        bf16x8 ah, am, al;
#pragma unroll
        for (int j = 0; j < 8; j++) {
            float v = xb[(cc * 32 + quad * 8 + j) * HW];
            u16 h, m, l; split3(v, h, m, l);
            ah[j] = (short)h; am[j] = (short)m; al[j] = (short)l;
        }
#pragma unroll
        for (int dt = 0; dt < 2; dt++) {
            int dtg = dhalf * 8 + wave * 2 + dt;
            int off = ((dtg * 8 + cc) * 64 + lane) * 8;   // packed: 1 KB/wave burst
            const bf16x8 bh = *(const bf16x8*)(wh + off);
            const bf16x8 bm = *(const bf16x8*)(wm + off);
            const bf16x8 bl = *(const bf16x8*)(wl + off);
            acc[dt] = MFMA_BF16(ah, bh, acc[dt]);
            acc[dt] = MFMA_BF16(am, bh, acc[dt]);
            acc[dt] = MFMA_BF16(ah, bm, acc[dt]);
            acc[dt] = MFMA_BF16(al, bh, acc[dt]);
            acc[dt] = MFMA_BF16(am, bm, acc[dt]);
            acc[dt] = MFMA_BF16(ah, bl, acc[dt]);
        }
    }

#pragma unroll
    for (int dt = 0; dt < 2; dt++) {
        int dtg = dhalf * 8 + wave * 2 + dt;
        int d = dtg * 16 + l15;              // C-layout: col = lane&15
        float bv = bias[d];
#pragma unroll
        for (int r = 0; r < 4; r++) {
            int n = n0 + quad * 4 + r;       // C-layout: row = quad*4 + reg
            float v = acc[dt][r] + bv;
            xp[n * DD + d] = v;
            xpH[n * DD + d] = f2b(v);
        }
    }
}

// ---------------------------------------------------------------------------
// K2: approx distance GEMM (32x32x16 MFMA) + fused argmin-candidate select.
// R18: KSPLIT=8 — 1024 codes per split (32 kc iterations), grid (128, 8).
// Same total MFMA work and sync structure (verified local optimum); key id
// field widens 9 -> 10 bits (mask 0xFFFFFC00; orv = kc<<5|col, kc<=31 fits).
// Distance-key granularity 0.06 << near-min gaps (~10) — comparator safe.
// Emits top-2 per split -> 16 candidates/row (rescore bytes halve).
// C/D (verified m74/m101): col = lane&31, row = (reg&3)+8*(reg>>2)+4*(lane>>5).
__global__ __launch_bounds__(256, 3) void k_dist(const u16* __restrict__ xpH,
                                                 const u16* __restrict__ cbTh,
                                                 const float* __restrict__ negC0,
                                                 u32* __restrict__ pkey) {
    __shared__ __align__(16) u16 tile[2][KROWS * 256];  // 2 x 16 KB
    int tid = threadIdx.x, wave = tid >> 6, lane = tid & 63;
    int col = lane & 31, half = lane >> 5;
    int n0 = blockIdx.x * 128 + wave * 32;
    int ksbase = blockIdx.y * (KK / KSPLIT);   // 1024 codes per split

    // A-frags resident: 16 ks (row = col, dims ks*16 + half*8 + j)
    bf16x8 Ah[16];
    {
        const u16* ab = xpH + (size_t)(n0 + col) * DD + half * 8;
#pragma unroll
        for (int ks = 0; ks < 16; ks++)
            Ah[ks] = *(const bf16x8*)(ab + ks * 16);
    }

    u32 key[16];
#pragma unroll
    for (int g = 0; g < 16; g++) key[g] = 0xffffffffu;

#define STAGE(bufi, kglob_)                                                    \
    {                                                                          \
        int kg_ = (kglob_);                                                    \
        _Pragma("unroll")                                                      \
        for (int c = 0; c < 4; c++) {                                          \
            int chunk = wave * 4 + c;                                          \
            int row = chunk * 2 + (lane >> 5);                                 \
            int g = (lane & 31) ^ (row & 7);                                   \
            const u16* src = cbTh + (size_t)(kg_ + row) * DD + g * 8;          \
            async_load16(src, &tile[bufi][chunk * 512]);                       \
        }                                                                      \
    }

    STAGE(0, ksbase);
    float nc_cur = negC0[ksbase + col];
    __syncthreads();

    for (int kc = 0; kc < 32; kc++) {
        int buf = kc & 1;
        float nc_next = 0.f;
        if (kc < 31) {
            STAGE(buf ^ 1, ksbase + (kc + 1) * KROWS);
            nc_next = negC0[ksbase + (kc + 1) * KROWS + col];
        }

        f32x16 a0, a1;
#pragma unroll
        for (int g = 0; g < 16; g++) { a0[g] = nc_cur; a1[g] = 0.f; }

        const u16* trow = &tile[buf][col * 256];
#pragma unroll
        for (int ks = 0; ks < 8; ks++) {
            int g0 = ((2 * ks) * 2 + half) ^ (col & 7);
            int g1 = ((2 * ks + 1) * 2 + half) ^ (col & 7);
            const bf16x8 Bf0 = *(const bf16x8*)(trow + g0 * 8);
            const bf16x8 Bf1 = *(const bf16x8*)(trow + g1 * 8);
            a0 = MFMA32_BF16(Ah[2 * ks], Bf0, a0);
            a1 = MFMA32_BF16(Ah[2 * ks + 1], Bf1, a1);
        }

        u32 orv = ((u32)kc << 5) | (u32)col;   // 10-bit id within split
#pragma unroll
        for (int g = 0; g < 16; g++) {
            u32 kb = (f2u(a0[g] + a1[g]) & 0xFFFFFC00u) | orv;
            key[g] = min(key[g], kb);
        }
        nc_cur = nc_next;
        __syncthreads();  // drains prefetch + guards buffers
    }
#undef STAGE

    // top-2 across the 32 lanes (cols) sharing each C row
#pragma unroll
    for (int g = 0; g < 16; g++) {
        u32 k1 = key[g], k2 = 0xffffffffu;
#pragma unroll
        for (int m = 1; m < 32; m <<= 1) {
            u32 o1 = (u32)__shfl_xor((int)k1, m, 64);
            u32 o2 = (u32)__shfl_xor((int)k2, m, 64);
            u32 mx = max(k1, o1);
            k1 = min(k1, o1);
            k2 = min(min(k2, o2), mx);
        }
        if (col == 0) {
            int row = (g & 3) + 8 * (g >> 2) + 4 * half;
            int n = n0 + row;
            int base = (n * KSPLIT + blockIdx.y) * 2;
            pkey[base]     = (u32)ksbase + (k1 & 1023u);
            pkey[base + 1] = (u32)ksbase + (k2 & 1023u);
        }
    }
}

// ---------------------------------------------------------------------------
// K3: exact fp64 rescore of 16 candidates per row (R18: halved by KSPLIT=8).
// TLP x coalesced (R17 structure): block = 4 waves = TWO rows; waves 0-1 ->
// row 2bx (8 candidates each), waves 2-3 -> row 2bx+1. Contiguous 128 B
// spans per instruction. Comparator is lexicographic (value,index) min —
// total order, reduction-order changes are result-identical.
__global__ __launch_bounds__(256) void k_rescore(const float* __restrict__ xp,
                                                 const float* __restrict__ cbT,
                                                 const u32* __restrict__ pkey,
                                                 u32* __restrict__ idxv,
                                                 float* __restrict__ outIdx,
                                                 float* __restrict__ pmin) {
    __shared__ double sbv[4];
    __shared__ u32 sbi[4];
    int tid = threadIdx.x, wave = tid >> 6, lane = tid & 63;
    int rowh = wave >> 1;                    // 0/1: which row of the pair
    int wsub = wave & 1;                     // which 8-candidate half
    int n = blockIdx.x * 2 + rowh;
    int sub = lane >> 3;
    int oct = lane & 7;

    f32x4 xv[8];
    const float* xb = xp + n * DD;
#pragma unroll
    for (int t = 0; t < 8; t++) xv[t] = *(const f32x4*)(xb + (t * 8 + oct) * 4);

    // this wave's candidate for this sub-group (8 lanes share one candidate)
    u32 kg = pkey[n * 16 + wsub * 8 + sub] & 8191u;

    const float* cv = cbT + (size_t)kg * DD;
    double s = 0.0;
#pragma unroll
    for (int t = 0; t < 8; t++) {
        f32x4 cvv = *(const f32x4*)(cv + (t * 8 + oct) * 4);
#pragma unroll
        for (int q = 0; q < 4; q++) {
            double d = (double)xv[t][q] - (double)cvv[q];
            s += d * d;
        }
    }
    s += __shfl_xor(s, 1, 64);
    s += __shfl_xor(s, 2, 64);
    s += __shfl_xor(s, 4, 64);

    double bestv = s;
    u32 besti = kg;
#pragma unroll
    for (int m = 8; m < 64; m <<= 1) {
        double ov = __shfl_xor(bestv, m, 64);
        u32 oi = (u32)__shfl_xor((int)besti, m, 64);
        if (ov < bestv || (ov == bestv && oi < besti)) { bestv = ov; besti = oi; }
    }
    if (lane == 0) { sbv[wave] = bestv; sbi[wave] = besti; }
    __syncthreads();
    if ((tid & 127) == 0) {
        int rh = tid >> 7;                   // 0 or 1
        double bv = sbv[rh * 2];     u32 bi = sbi[rh * 2];
        double ov = sbv[rh * 2 + 1]; u32 oi = sbi[rh * 2 + 1];
        if (ov < bv || (ov == bv && oi < bi)) { bv = ov; bi = oi; }
        int nn = blockIdx.x * 2 + rh;
        idxv[nn] = bi;
        outIdx[nn] = (float)bi;
        pmin[nn] = (float)bv;
    }
}

// ---------------------------------------------------------------------------
// K5 (k_final folded in): gather quantized (B,D,H,W) fp32 via LDS transpose
// tiles; block NN/32 reduces pmin -> outDiff. Coalesced cbT staging reads.
// Rewrites ALL of d_out chunk 0.
__global__ __launch_bounds__(256) void k_gather(const float* __restrict__ cbT,
                                                const u32* __restrict__ idxv,
                                                const float* __restrict__ pmin,
                                                float* __restrict__ out0,
                                                float* __restrict__ outDiff) {
    if (blockIdx.x == NN / 32) {
        // fused k_final: diff = sum(pmin)/(N*D), fp64. 256 threads x 64 vals.
        __shared__ double sm[4];
        int tid = threadIdx.x, lane = tid & 63, wv = tid >> 6;
        double s = 0.0;
#pragma unroll
        for (int i = 0; i < 64; i++) s += (double)pmin[i * 256 + tid];
#pragma unroll
        for (int m = 1; m < 64; m <<= 1) s += __shfl_xor(s, m, 64);
        if (lane == 0) sm[wv] = s;
        __syncthreads();
        if (tid == 0)
            outDiff[0] = (float)((sm[0] + sm[1] + sm[2] + sm[3]) * (1.0 / (double)OUT0));
        return;
    }

    __shared__ float tile[32 * 260];
    int tid = threadIdx.x;
    int n0 = blockIdx.x * 32;
    int b = n0 >> 10, hw0 = n0 & 1023;

    {
        int r = tid >> 3, seg = tid & 7;
        u32 k = idxv[n0 + r] & 8191u;
        const float* src = cbT + (size_t)k * DD;
        float* dst = tile + r * 260;
#pragma unroll
        for (int j = 0; j < 8; j++)
            *(f32x4*)(dst + (j * 8 + seg) * 4) = *(const f32x4*)(src + (j * 8 + seg) * 4);
    }
    __syncthreads();
    {
        int hw = tid & 31, dq = tid >> 5;
        const float* trow = tile + hw * 260;
        float* obase = out0 + ((size_t)b * DD) * HW + hw0 + hw;
#pragma unroll
        for (int dj = 0; dj < 32; dj++) {
            int d = dq * 32 + dj;
            obase[(size_t)d * HW] = trow[d];
        }
    }
}

// ---------------------------------------------------------------------------
extern "C" void kernel_launch(void* const* d_in, const int* in_sizes, int n_in,
                              void* d_out, int out_size, void* d_ws, size_t ws_size,
                              hipStream_t stream) {
    const float* x = nullptr; const float* Wm = nullptr;
    const float* bias = nullptr; const float* cb = nullptr;
    for (int i = 0; i < n_in; i++) {
        switch (in_sizes[i]) {
            case 4194304: x    = (const float*)d_in[i]; break;  // (16,256,32,32)
            case 65536:   Wm   = (const float*)d_in[i]; break;  // (256,256)
            case 256:     bias = (const float*)d_in[i]; break;  // (256,)
            case 2097152: cb   = (const float*)d_in[i]; break;  // (256,8192)
        }
    }

    // d_out is FP32: [quantized (4194304) | diff (1) | indices (16384)]
    float* out0    = (float*)d_out;
    float* outDiff = (float*)d_out + OUT0;
    float* outIdx  = (float*)d_out + OUT0 + 1;

    // Transient scratch inside d_out chunk 0 (16.78 MB; every byte rewritten
    // by k_gather before the harness reads):
    char* o = (char*)d_out;
    u16*   cbTh = (u16*)o;                       // [0, 4 MB)
    u32*   pkey = (u32*)(o + 4194304);           // [4 MB, 5 MB) — 1 MB now
    u16*   wh   = (u16*)(o + 6291456);           // 128 KB
    u16*   wm   = (u16*)(o + 6422528);           // 128 KB
    u16*   wl   = (u16*)(o + 6553600);           // 128 KB
    u16*   xpH  = (u16*)(o + 6750208);           // 8 MB  (N,D) bf16 -> ends 14.75 MB

    // Workspace (~25.33 MB, footprint that passed in rounds 4-9):
    char* w = (char*)d_ws;
    float* cbT   = (float*)(w);                  // 8 MB  (K,D) fp32
    float* xp    = (float*)(w + 8388608);        // 16 MB (N,D) fp32
    float* negC0 = (float*)(w + 25165824);       // 32 KB
    u32*   idxv  = (u32*)(w + 25198592);         // 64 KB
    float* pmin  = (float*)(w + 25264128);       // 64 KB

    k_prep<<<2560, 256, 0, stream>>>(cb, Wm, cbT, cbTh, negC0, wh, wm, wl);
    k_proj<<<NN / 8, 256, 0, stream>>>(x, wh, wm, wl, bias, xp, xpH);
    k_dist<<<dim3(NN / 128, KSPLIT), 256, 0, stream>>>(xpH, cbTh, negC0, pkey);
    k_rescore<<<NN / 2, 256, 0, stream>>>(xp, cbT, pkey, idxv, outIdx, pmin);
    k_gather<<<NN / 32 + 1, 256, 0, stream>>>(cbT, idxv, pmin, out0, outDiff);
}

// Round 19
// 201.879 us; speedup vs baseline: 2.3943x; 1.0487x over previous
//
#include <hip/hip_runtime.h>

typedef short bf16x8 __attribute__((ext_vector_type(8)));
typedef float f32x4 __attribute__((ext_vector_type(4)));
typedef float f32x16 __attribute__((ext_vector_type(16)));
using u16 = unsigned short;
using u32 = unsigned int;

#define MFMA_BF16(A, B, C) __builtin_amdgcn_mfma_f32_16x16x32_bf16((A), (B), (C), 0, 0, 0)
#define MFMA32_BF16(A, B, C) __builtin_amdgcn_mfma_f32_32x32x16_bf16((A), (B), (C), 0, 0, 0)

#define CC 256
#define DD 256
#define KK 8192
#define NN 16384     // B*H*W
#define HW 1024      // H*W
#define OUT0 4194304 // B*D*H*W
#define KSPLIT 8     // 1024-code splits (verified best for k_dist)
#define KROWS 32     // k-rows (codes) per LDS tile (verified best)

static __device__ __forceinline__ float b2f(u16 u) {
    union { u32 i; float f; } v; v.i = ((u32)u) << 16; return v.f;
}
static __device__ __forceinline__ u16 f2b(float f) {  // RNE fp32 -> bf16
    union { float f; u32 i; } v; v.f = f;
    u32 x = v.i;
    u32 r = (x + 0x7fffu + ((x >> 16) & 1u)) >> 16;
    return (u16)r;
}
static __device__ __forceinline__ u32 f2u(float f) {
    union { float f; u32 u; } v; v.f = f; return v.u;
}
static __device__ __forceinline__ void split3(float v, u16& h, u16& m, u16& l) {
    h = f2b(v); float r1 = v - b2f(h);
    m = f2b(r1); float r2 = r1 - b2f(m);
    l = f2b(r2);
}

typedef __attribute__((address_space(1))) const u32 GlbU32;
typedef __attribute__((address_space(3))) u32 LdsU32;
static __device__ __forceinline__ void async_load16(const void* g, void* l) {
    __builtin_amdgcn_global_load_lds((GlbU32*)g, (LdsU32*)l, 16, 0, 0);
}

// ---------------------------------------------------------------------------
// K0 (fused prep): blocks [0,2048): transpose cb -> cbT fp32 + cbTh bf16;
// blocks [2048,2304): negC0[k] = -0.5*(||c_k||^2 + 1024);
// blocks [2304,2560): 3-way bf16 split of conv_w into FRAGMENT-PACKED layout
// (R16): wpack index t = ((dtg*8+cc)*64 + lane)*8 + j.
__global__ __launch_bounds__(256) void k_prep(const float* __restrict__ cb,
                                              const float* __restrict__ Wm,
                                              float* __restrict__ cbT,
                                              u16* __restrict__ cbTh,
                                              float* __restrict__ negC0,
                                              u16* __restrict__ wh,
                                              u16* __restrict__ wm,
                                              u16* __restrict__ wl) {
    int bx = blockIdx.x, tid = threadIdx.x;
    if (bx < 2048) {
        __shared__ float tile[32][33];
        int k0 = (bx & 255) * 32, d0 = (bx >> 8) * 32;
        int tx = tid & 31, ty = tid >> 5;  // 32 x 8
#pragma unroll
        for (int i = 0; i < 4; i++) {
            int d = d0 + ty + i * 8;
            tile[ty + i * 8][tx] = cb[d * KK + k0 + tx];
        }
        __syncthreads();
#pragma unroll
        for (int i = 0; i < 4; i++) {
            int k = k0 + ty + i * 8;
            float v = tile[tx][ty + i * 8];
            cbT[k * DD + d0 + tx] = v;
            cbTh[k * DD + d0 + tx] = f2b(v);
        }
    } else if (bx < 2304) {
        __shared__ float sm[8][32];
        int kl = tid & 31, dg = tid >> 5;
        int k = (bx - 2048) * 32 + kl;
        float s = 0.f;
#pragma unroll
        for (int j = 0; j < 32; j++) {
            float v = cb[(size_t)(dg * 32 + j) * KK + k];
            s += v * v;
        }
        sm[dg][kl] = s;
        __syncthreads();
        if (tid < 32) {
            float t = 0.f;
#pragma unroll
            for (int g = 0; g < 8; g++) t += sm[g][tid];
            negC0[(bx - 2048) * 32 + tid] = -0.5f * (t + 1024.f);
        }
    } else {
        int t = (bx - 2304) * 256 + tid;      // packed index
        int j    = t & 7;
        int lane = (t >> 3) & 63;
        int cc   = (t >> 9) & 7;
        int dtg  = t >> 12;
        int l15 = lane & 15, quad = lane >> 4;
        int src = (dtg * 16 + l15) * CC + cc * 32 + quad * 8 + j;
        u16 h, m, l; split3(Wm[src], h, m, l);
        wh[t] = h; wm[t] = m; wl[t] = l;
    }
}

// ---------------------------------------------------------------------------
// K1: xp = x_r @ W^T + b via bf16x3 split MFMA (6 terms ~ fp32 accuracy).
// R16 structure (verified): fragment-packed W reads + dt-split x2.
__global__ __launch_bounds__(256) void k_proj(const float* __restrict__ x,
                                              const u16* __restrict__ wh,
                                              const u16* __restrict__ wm,
                                              const u16* __restrict__ wl,
                                              const float* __restrict__ bias,
                                              float* __restrict__ xp,
                                              u16* __restrict__ xpH) {
    int tid = threadIdx.x;
    int wave = tid >> 6, lane = tid & 63;
    int quad = lane >> 4, l15 = lane & 15;
    int n0 = (blockIdx.x >> 1) * 16;
    int dhalf = blockIdx.x & 1;              // which 128-d half
    int n_a = n0 + l15;
    const float* xb = x + (n_a >> 10) * (CC * HW) + (n_a & (HW - 1));

    f32x4 acc[2];
#pragma unroll
    for (int i = 0; i < 2; i++) acc[i] = (f32x4){0.f, 0.f, 0.f, 0.f};

#pragma unroll
    for (int cc = 0; cc < 8; cc++) {
        bf16x8 ah, am, al;
#pragma unroll
        for (int j = 0; j < 8; j++) {
            float v = xb[(cc * 32 + quad * 8 + j) * HW];
            u16 h, m, l; split3(v, h, m, l);
            ah[j] = (short)h; am[j] = (short)m; al[j] = (short)l;
        }
#pragma unroll
        for (int dt = 0; dt < 2; dt++) {
            int dtg = dhalf * 8 + wave * 2 + dt;
            int off = ((dtg * 8 + cc) * 64 + lane) * 8;   // packed: 1 KB/wave burst
            const bf16x8 bh = *(const bf16x8*)(wh + off);
            const bf16x8 bm = *(const bf16x8*)(wm + off);
            const bf16x8 bl = *(const bf16x8*)(wl + off);
            acc[dt] = MFMA_BF16(ah, bh, acc[dt]);
            acc[dt] = MFMA_BF16(am, bh, acc[dt]);
            acc[dt] = MFMA_BF16(ah, bm, acc[dt]);
            acc[dt] = MFMA_BF16(al, bh, acc[dt]);
            acc[dt] = MFMA_BF16(am, bm, acc[dt]);
            acc[dt] = MFMA_BF16(ah, bl, acc[dt]);
        }
    }

#pragma unroll
    for (int dt = 0; dt < 2; dt++) {
        int dtg = dhalf * 8 + wave * 2 + dt;
        int d = dtg * 16 + l15;              // C-layout: col = lane&15
        float bv = bias[d];
#pragma unroll
        for (int r = 0; r < 4; r++) {
            int n = n0 + quad * 4 + r;       // C-layout: row = quad*4 + reg
            float v = acc[dt][r] + bv;
            xp[n * DD + d] = v;
            xpH[n * DD + d] = f2b(v);
        }
    }
}

// ---------------------------------------------------------------------------
// K2: approx distance GEMM (32x32x16 MFMA) + fused argmin-candidate select.
// R18 structure (verified best, 88.4 us): KSPLIT=8, 32 kc/block, KROWS=32,
// XOR swizzle, 2 LDS buffers, __syncthreads per kc, ILP-2 MFMA chains.
// R19: the final per-split top-2 stores now pack FULL KEYS:
// bits 13-31 = truncated approx-distance float bits, bits 0-12 = GLOBAL code
// id. Keys are uniformly negative floats (a = x.c - 0.5||c||^2 - 512 ~
// -600 +- 50; max x.c ~ +90 << 596) so u32-min ordering is monotone in
// distance ACROSS splits — rescore can rank all 16 candidates by approx
// distance without touching memory.
// C/D (verified m74/m101): col = lane&31, row = (reg&3)+8*(reg>>2)+4*(lane>>5).
__global__ __launch_bounds__(256, 3) void k_dist(const u16* __restrict__ xpH,
                                                 const u16* __restrict__ cbTh,
                                                 const float* __restrict__ negC0,
                                                 u32* __restrict__ pkey) {
    __shared__ __align__(16) u16 tile[2][KROWS * 256];  // 2 x 16 KB
    int tid = threadIdx.x, wave = tid >> 6, lane = tid & 63;
    int col = lane & 31, half = lane >> 5;
    int n0 = blockIdx.x * 128 + wave * 32;
    int ksbase = blockIdx.y * (KK / KSPLIT);   // 1024 codes per split

    // A-frags resident: 16 ks (row = col, dims ks*16 + half*8 + j)
    bf16x8 Ah[16];
    {
        const u16* ab = xpH + (size_t)(n0 + col) * DD + half * 8;
#pragma unroll
        for (int ks = 0; ks < 16; ks++)
            Ah[ks] = *(const bf16x8*)(ab + ks * 16);
    }

    u32 key[16];
#pragma unroll
    for (int g = 0; g < 16; g++) key[g] = 0xffffffffu;

#define STAGE(bufi, kglob_)                                                    \
    {                                                                          \
        int kg_ = (kglob_);                                                    \
        _Pragma("unroll")                                                      \
        for (int c = 0; c < 4; c++) {                                          \
            int chunk = wave * 4 + c;                                          \
            int row = chunk * 2 + (lane >> 5);                                 \
            int g = (lane & 31) ^ (row & 7);                                   \
            const u16* src = cbTh + (size_t)(kg_ + row) * DD + g * 8;          \
            async_load16(src, &tile[bufi][chunk * 512]);                       \
        }                                                                      \
    }

    STAGE(0, ksbase);
    float nc_cur = negC0[ksbase + col];
    __syncthreads();

    for (int kc = 0; kc < 32; kc++) {
        int buf = kc & 1;
        float nc_next = 0.f;
        if (kc < 31) {
            STAGE(buf ^ 1, ksbase + (kc + 1) * KROWS);
            nc_next = negC0[ksbase + (kc + 1) * KROWS + col];
        }

        f32x16 a0, a1;
#pragma unroll
        for (int g = 0; g < 16; g++) { a0[g] = nc_cur; a1[g] = 0.f; }

        const u16* trow = &tile[buf][col * 256];
#pragma unroll
        for (int ks = 0; ks < 8; ks++) {
            int g0 = ((2 * ks) * 2 + half) ^ (col & 7);
            int g1 = ((2 * ks + 1) * 2 + half) ^ (col & 7);
            const bf16x8 Bf0 = *(const bf16x8*)(trow + g0 * 8);
            const bf16x8 Bf1 = *(const bf16x8*)(trow + g1 * 8);
            a0 = MFMA32_BF16(Ah[2 * ks], Bf0, a0);
            a1 = MFMA32_BF16(Ah[2 * ks + 1], Bf1, a1);
        }

        u32 orv = ((u32)kc << 5) | (u32)col;   // 10-bit id within split
#pragma unroll
        for (int g = 0; g < 16; g++) {
            u32 kb = (f2u(a0[g] + a1[g]) & 0xFFFFFC00u) | orv;
            key[g] = min(key[g], kb);
        }
        nc_cur = nc_next;
        __syncthreads();  // drains prefetch + guards buffers
    }
#undef STAGE

    // top-2 across the 32 lanes (cols) sharing each C row
#pragma unroll
    for (int g = 0; g < 16; g++) {
        u32 k1 = key[g], k2 = 0xffffffffu;
#pragma unroll
        for (int m = 1; m < 32; m <<= 1) {
            u32 o1 = (u32)__shfl_xor((int)k1, m, 64);
            u32 o2 = (u32)__shfl_xor((int)k2, m, 64);
            u32 mx = max(k1, o1);
            k1 = min(k1, o1);
            k2 = min(min(k2, o2), mx);
        }
        if (col == 0) {
            int row = (g & 3) + 8 * (g >> 2) + 4 * half;
            int n = n0 + row;
            int base = (n * KSPLIT + blockIdx.y) * 2;
            // full key: [31:13] approx-distance bits | [12:0] global code id
            pkey[base]     = (k1 & 0xFFFFE000u) | ((u32)ksbase + (k1 & 1023u));
            pkey[base + 1] = (k2 & 0xFFFFE000u) | ((u32)ksbase + (k2 & 1023u));
        }
    }
}

// ---------------------------------------------------------------------------
// K3: exact fp64 rescore. R19: APPROX-TOP-4 PRE-FILTER — one wave per row
// reads the 16 full keys (distance|id, cross-split comparable), extracts the
// 4 smallest via repeated 16-lane min-reduce (ids globally unique -> no
// duplicate masking hazard), then fp64-rescores ONLY those 4 codes (4 KB/row
// vs 16 KB). Safety: true argmin outside approx-top-4 needs 4 codes beating
// it under sigma~0.18 noise against ~9.3 expected near-min gaps (z~50 each).
// Gather: cand = lane>>4 (4 groups x 16 lanes); per instruction 16 lanes
// cover 256 B contiguous. Named cand regs + select chain (no runtime-indexed
// array -> no scratch, rule #20).
__global__ __launch_bounds__(256) void k_rescore(const float* __restrict__ xp,
                                                 const float* __restrict__ cbT,
                                                 const u32* __restrict__ pkey,
                                                 u32* __restrict__ idxv,
                                                 float* __restrict__ outIdx,
                                                 float* __restrict__ pmin) {
    int tid = threadIdx.x, wave = tid >> 6, lane = tid & 63;
    int n = blockIdx.x * 4 + wave;

    u32 key = (lane < 16) ? pkey[n * 16 + lane] : 0xffffffffu;

    u32 cand0, cand1, cand2, cand3;
#define EXTRACT(C)                                                             \
    {                                                                          \
        u32 kmin = key;                                                        \
        kmin = min(kmin, (u32)__shfl_xor((int)kmin, 1, 64));                   \
        kmin = min(kmin, (u32)__shfl_xor((int)kmin, 2, 64));                   \
        kmin = min(kmin, (u32)__shfl_xor((int)kmin, 4, 64));                   \
        kmin = min(kmin, (u32)__shfl_xor((int)kmin, 8, 64));                   \
        C = (u32)__shfl((int)kmin, 0, 64);                                     \
        if (key == C) key = 0xffffffffu;                                       \
    }
    EXTRACT(cand0)
    EXTRACT(cand1)
    EXTRACT(cand2)
    EXTRACT(cand3)
#undef EXTRACT

    int g = lane >> 4, sl = lane & 15;
    u32 ck = (g == 0) ? cand0 : (g == 1) ? cand1 : (g == 2) ? cand2 : cand3;
    u32 kg = ck & 8191u;

    const float* cv = cbT + (size_t)kg * DD;
    const float* xb = xp + n * DD;
    double s = 0.0;
#pragma unroll
    for (int t = 0; t < 4; t++) {
        f32x4 cvv = *(const f32x4*)(cv + (t * 16 + sl) * 4);
        f32x4 xvv = *(const f32x4*)(xb + (t * 16 + sl) * 4);
#pragma unroll
        for (int q = 0; q < 4; q++) {
            double d = (double)xvv[q] - (double)cvv[q];
            s += d * d;
        }
    }
    // reduce within each 16-lane group
    s += __shfl_xor(s, 1, 64);
    s += __shfl_xor(s, 2, 64);
    s += __shfl_xor(s, 4, 64);
    s += __shfl_xor(s, 8, 64);

    // compare across the 4 groups
    double bestv = s;
    u32 besti = kg;
#pragma unroll
    for (int m = 16; m < 64; m <<= 1) {
        double ov = __shfl_xor(bestv, m, 64);
        u32 oi = (u32)__shfl_xor((int)besti, m, 64);
        if (ov < bestv || (ov == bestv && oi < besti)) { bestv = ov; besti = oi; }
    }
    if (lane == 0) {
        idxv[n] = besti;
        outIdx[n] = (float)besti;
        pmin[n] = (float)bestv;
    }
}

// ---------------------------------------------------------------------------
// K5 (k_final folded in): gather quantized (B,D,H,W) fp32 via LDS transpose
// tiles; block NN/32 reduces pmin -> outDiff. Coalesced cbT staging reads.
// Rewrites ALL of d_out chunk 0.
__global__ __launch_bounds__(256) void k_gather(const float* __restrict__ cbT,
                                                const u32* __restrict__ idxv,
                                                const float* __restrict__ pmin,
                                                float* __restrict__ out0,
                                                float* __restrict__ outDiff) {
    if (blockIdx.x == NN / 32) {
        // fused k_final: diff = sum(pmin)/(N*D), fp64. 256 threads x 64 vals.
        __shared__ double sm[4];
        int tid = threadIdx.x, lane = tid & 63, wv = tid >> 6;
        double s = 0.0;
#pragma unroll
        for (int i = 0; i < 64; i++) s += (double)pmin[i * 256 + tid];
#pragma unroll
        for (int m = 1; m < 64; m <<= 1) s += __shfl_xor(s, m, 64);
        if (lane == 0) sm[wv] = s;
        __syncthreads();
        if (tid == 0)
            outDiff[0] = (float)((sm[0] + sm[1] + sm[2] + sm[3]) * (1.0 / (double)OUT0));
        return;
    }

    __shared__ float tile[32 * 260];
    int tid = threadIdx.x;
    int n0 = blockIdx.x * 32;
    int b = n0 >> 10, hw0 = n0 & 1023;

    {
        int r = tid >> 3, seg = tid & 7;
        u32 k = idxv[n0 + r] & 8191u;
        const float* src = cbT + (size_t)k * DD;
        float* dst = tile + r * 260;
#pragma unroll
        for (int j = 0; j < 8; j++)
            *(f32x4*)(dst + (j * 8 + seg) * 4) = *(const f32x4*)(src + (j * 8 + seg) * 4);
    }
    __syncthreads();
    {
        int hw = tid & 31, dq = tid >> 5;
        const float* trow = tile + hw * 260;
        float* obase = out0 + ((size_t)b * DD) * HW + hw0 + hw;
#pragma unroll
        for (int dj = 0; dj < 32; dj++) {
            int d = dq * 32 + dj;
            obase[(size_t)d * HW] = trow[d];
        }
    }
}

// ---------------------------------------------------------------------------
extern "C" void kernel_launch(void* const* d_in, const int* in_sizes, int n_in,
                              void* d_out, int out_size, void* d_ws, size_t ws_size,
                              hipStream_t stream) {
    const float* x = nullptr; const float* Wm = nullptr;
    const float* bias = nullptr; const float* cb = nullptr;
    for (int i = 0; i < n_in; i++) {
        switch (in_sizes[i]) {
            case 4194304: x    = (const float*)d_in[i]; break;  // (16,256,32,32)
            case 65536:   Wm   = (const float*)d_in[i]; break;  // (256,256)
            case 256:     bias = (const float*)d_in[i]; break;  // (256,)
            case 2097152: cb   = (const float*)d_in[i]; break;  // (256,8192)
        }
    }

    // d_out is FP32: [quantized (4194304) | diff (1) | indices (16384)]
    float* out0    = (float*)d_out;
    float* outDiff = (float*)d_out + OUT0;
    float* outIdx  = (float*)d_out + OUT0 + 1;

    // Transient scratch inside d_out chunk 0 (16.78 MB; every byte rewritten
    // by k_gather before the harness reads):
    char* o = (char*)d_out;
    u16*   cbTh = (u16*)o;                       // [0, 4 MB)
    u32*   pkey = (u32*)(o + 4194304);           // [4 MB, 5 MB) — 1 MB
    u16*   wh   = (u16*)(o + 6291456);           // 128 KB
    u16*   wm   = (u16*)(o + 6422528);           // 128 KB
    u16*   wl   = (u16*)(o + 6553600);           // 128 KB
    u16*   xpH  = (u16*)(o + 6750208);           // 8 MB  (N,D) bf16 -> ends 14.75 MB

    // Workspace (~25.33 MB, footprint that passed in rounds 4-9):
    char* w = (char*)d_ws;
    float* cbT   = (float*)(w);                  // 8 MB  (K,D) fp32
    float* xp    = (float*)(w + 8388608);        // 16 MB (N,D) fp32
    float* negC0 = (float*)(w + 25165824);       // 32 KB
    u32*   idxv  = (u32*)(w + 25198592);         // 64 KB
    float* pmin  = (float*)(w + 25264128);       // 64 KB

    k_prep<<<2560, 256, 0, stream>>>(cb, Wm, cbT, cbTh, negC0, wh, wm, wl);
    k_proj<<<NN / 8, 256, 0, stream>>>(x, wh, wm, wl, bias, xp, xpH);
    k_dist<<<dim3(NN / 128, KSPLIT), 256, 0, stream>>>(xpH, cbTh, negC0, pkey);
    k_rescore<<<NN / 4, 256, 0, stream>>>(xp, cbT, pkey, idxv, outIdx, pmin);
    k_gather<<<NN / 32 + 1, 256, 0, stream>>>(cbT, idxv, pmin, out0, outDiff);
}

// Round 20
// 198.112 us; speedup vs baseline: 2.4398x; 1.0190x over previous
//
#include <hip/hip_runtime.h>

typedef short bf16x8 __attribute__((ext_vector_type(8)));
typedef float f32x4 __attribute__((ext_vector_type(4)));
typedef float f32x16 __attribute__((ext_vector_type(16)));
using u16 = unsigned short;
using u32 = unsigned int;

#define MFMA_BF16(A, B, C) __builtin_amdgcn_mfma_f32_16x16x32_bf16((A), (B), (C), 0, 0, 0)
#define MFMA32_BF16(A, B, C) __builtin_amdgcn_mfma_f32_32x32x16_bf16((A), (B), (C), 0, 0, 0)

#define CC 256
#define DD 256
#define KK 8192
#define NN 16384     // B*H*W
#define HW 1024      // H*W
#define OUT0 4194304 // B*D*H*W
#define KSPLIT 4     // R20: 8 -> 4 (2048-code splits; fewer prologues, zero tail)
#define KROWS 32     // k-rows (codes) per LDS tile (verified best)

static __device__ __forceinline__ float b2f(u16 u) {
    union { u32 i; float f; } v; v.i = ((u32)u) << 16; return v.f;
}
static __device__ __forceinline__ u16 f2b(float f) {  // RNE fp32 -> bf16
    union { float f; u32 i; } v; v.f = f;
    u32 x = v.i;
    u32 r = (x + 0x7fffu + ((x >> 16) & 1u)) >> 16;
    return (u16)r;
}
static __device__ __forceinline__ u32 f2u(float f) {
    union { float f; u32 u; } v; v.f = f; return v.u;
}
static __device__ __forceinline__ void split3(float v, u16& h, u16& m, u16& l) {
    h = f2b(v); float r1 = v - b2f(h);
    m = f2b(r1); float r2 = r1 - b2f(m);
    l = f2b(r2);
}

typedef __attribute__((address_space(1))) const u32 GlbU32;
typedef __attribute__((address_space(3))) u32 LdsU32;
static __device__ __forceinline__ void async_load16(const void* g, void* l) {
    __builtin_amdgcn_global_load_lds((GlbU32*)g, (LdsU32*)l, 16, 0, 0);
}

// ---------------------------------------------------------------------------
// K0 (fused prep): blocks [0,2048): transpose cb -> cbT fp32 + cbTh bf16;
// blocks [2048,2304): negC0[k] = -0.5*(||c_k||^2 + 1024);
// blocks [2304,2560): 3-way bf16 split of conv_w into FRAGMENT-PACKED layout
// (R16): wpack index t = ((dtg*8+cc)*64 + lane)*8 + j.
__global__ __launch_bounds__(256) void k_prep(const float* __restrict__ cb,
                                              const float* __restrict__ Wm,
                                              float* __restrict__ cbT,
                                              u16* __restrict__ cbTh,
                                              float* __restrict__ negC0,
                                              u16* __restrict__ wh,
                                              u16* __restrict__ wm,
                                              u16* __restrict__ wl) {
    int bx = blockIdx.x, tid = threadIdx.x;
    if (bx < 2048) {
        __shared__ float tile[32][33];
        int k0 = (bx & 255) * 32, d0 = (bx >> 8) * 32;
        int tx = tid & 31, ty = tid >> 5;  // 32 x 8
#pragma unroll
        for (int i = 0; i < 4; i++) {
            int d = d0 + ty + i * 8;
            tile[ty + i * 8][tx] = cb[d * KK + k0 + tx];
        }
        __syncthreads();
#pragma unroll
        for (int i = 0; i < 4; i++) {
            int k = k0 + ty + i * 8;
            float v = tile[tx][ty + i * 8];
            cbT[k * DD + d0 + tx] = v;
            cbTh[k * DD + d0 + tx] = f2b(v);
        }
    } else if (bx < 2304) {
        __shared__ float sm[8][32];
        int kl = tid & 31, dg = tid >> 5;
        int k = (bx - 2048) * 32 + kl;
        float s = 0.f;
#pragma unroll
        for (int j = 0; j < 32; j++) {
            float v = cb[(size_t)(dg * 32 + j) * KK + k];
            s += v * v;
        }
        sm[dg][kl] = s;
        __syncthreads();
        if (tid < 32) {
            float t = 0.f;
#pragma unroll
            for (int g = 0; g < 8; g++) t += sm[g][tid];
            negC0[(bx - 2048) * 32 + tid] = -0.5f * (t + 1024.f);
        }
    } else {
        int t = (bx - 2304) * 256 + tid;      // packed index
        int j    = t & 7;
        int lane = (t >> 3) & 63;
        int cc   = (t >> 9) & 7;
        int dtg  = t >> 12;
        int l15 = lane & 15, quad = lane >> 4;
        int src = (dtg * 16 + l15) * CC + cc * 32 + quad * 8 + j;
        u16 h, m, l; split3(Wm[src], h, m, l);
        wh[t] = h; wm[t] = m; wl[t] = l;
    }
}

// ---------------------------------------------------------------------------
// K1: xp = x_r @ W^T + b via bf16x3 split MFMA (6 terms ~ fp32 accuracy).
// R16 structure (verified): fragment-packed W reads + dt-split x2.
__global__ __launch_bounds__(256) void k_proj(const float* __restrict__ x,
                                              const u16* __restrict__ wh,
                                              const u16* __restrict__ wm,
                                              const u16* __restrict__ wl,
                                              const float* __restrict__ bias,
                                              float* __restrict__ xp,
                                              u16* __restrict__ xpH) {
    int tid = threadIdx.x;
    int wave = tid >> 6, lane = tid & 63;
    int quad = lane >> 4, l15 = lane & 15;
    int n0 = (blockIdx.x >> 1) * 16;
    int dhalf = blockIdx.x & 1;              // which 128-d half
    int n_a = n0 + l15;
    const float* xb = x + (n_a >> 10) * (CC * HW) + (n_a & (HW - 1));

    f32x4 acc[2];
#pragma unroll
    for (int i = 0; i < 2; i++) acc[i] = (f32x4){0.f, 0.f, 0.f, 0.f};

#pragma unroll
    for (int cc = 0; cc < 8; cc++) {
        bf16x8 ah, am, al;
#pragma unroll
        for (int j = 0; j < 8; j++) {
            float v = xb[(cc * 32 + quad * 8 + j) * HW];
            u16 h, m, l; split3(v, h, m, l);
            ah[j] = (short)h; am[j] = (short)m; al[j] = (short)l;
        }
#pragma unroll
        for (int dt = 0; dt < 2; dt++) {
            int dtg = dhalf * 8 + wave * 2 + dt;
            int off = ((dtg * 8 + cc) * 64 + lane) * 8;   // packed: 1 KB/wave burst
            const bf16x8 bh = *(const bf16x8*)(wh + off);
            const bf16x8 bm = *(const bf16x8*)(wm + off);
            const bf16x8 bl = *(const bf16x8*)(wl + off);
            acc[dt] = MFMA_BF16(ah, bh, acc[dt]);
            acc[dt] = MFMA_BF16(am, bh, acc[dt]);
            acc[dt] = MFMA_BF16(ah, bm, acc[dt]);
            acc[dt] = MFMA_BF16(al, bh, acc[dt]);
            acc[dt] = MFMA_BF16(am, bm, acc[dt]);
            acc[dt] = MFMA_BF16(ah, bl, acc[dt]);
        }
    }

#pragma unroll
    for (int dt = 0; dt < 2; dt++) {
        int dtg = dhalf * 8 + wave * 2 + dt;
        int d = dtg * 16 + l15;              // C-layout: col = lane&15
        float bv = bias[d];
#pragma unroll
        for (int r = 0; r < 4; r++) {
            int n = n0 + quad * 4 + r;       // C-layout: row = quad*4 + reg
            float v = acc[dt][r] + bv;
            xp[n * DD + d] = v;
            xpH[n * DD + d] = f2b(v);
        }
    }
}

// ---------------------------------------------------------------------------
// K2: approx distance GEMM (32x32x16 MFMA) + fused argmin-candidate select.
// R20: KSPLIT=4 — 2048 codes per split (64 kc iterations), grid (128, 4) =
// 512 blocks = exactly 2 blocks/CU (zero dispatch tail; measured effective
// occupancy at KSPLIT=8 was already ~2 blocks/CU, so no residency loss).
// Sync structure unchanged (verified local optimum). In-split id widens to
// 11 bits (orv = kc<<5|col, kc<=63; accumulate mask 0xFFFFF800). Final store
// re-packs [31:13] = 19 approx-distance bits | [12:0] global id — identical
// field layout to the R19-verified rescore filter. Distance granularity
// ~0.5 << ~10 near-min gaps; stored minima share one float-exponent band so
// u32 ordering stays distance-monotone across splits.
// C/D (verified m74/m101): col = lane&31, row = (reg&3)+8*(reg>>2)+4*(lane>>5).
__global__ __launch_bounds__(256, 3) void k_dist(const u16* __restrict__ xpH,
                                                 const u16* __restrict__ cbTh,
                                                 const float* __restrict__ negC0,
                                                 u32* __restrict__ pkey) {
    __shared__ __align__(16) u16 tile[2][KROWS * 256];  // 2 x 16 KB
    int tid = threadIdx.x, wave = tid >> 6, lane = tid & 63;
    int col = lane & 31, half = lane >> 5;
    int n0 = blockIdx.x * 128 + wave * 32;
    int ksbase = blockIdx.y * (KK / KSPLIT);   // 2048 codes per split

    // A-frags resident: 16 ks (row = col, dims ks*16 + half*8 + j)
    bf16x8 Ah[16];
    {
        const u16* ab = xpH + (size_t)(n0 + col) * DD + half * 8;
#pragma unroll
        for (int ks = 0; ks < 16; ks++)
            Ah[ks] = *(const bf16x8*)(ab + ks * 16);
    }

    u32 key[16];
#pragma unroll
    for (int g = 0; g < 16; g++) key[g] = 0xffffffffu;

#define STAGE(bufi, kglob_)                                                    \
    {                                                                          \
        int kg_ = (kglob_);                                                    \
        _Pragma("unroll")                                                      \
        for (int c = 0; c < 4; c++) {                                          \
            int chunk = wave * 4 + c;                                          \
            int row = chunk * 2 + (lane >> 5);                                 \
            int g = (lane & 31) ^ (row & 7);                                   \
            const u16* src = cbTh + (size_t)(kg_ + row) * DD + g * 8;          \
            async_load16(src, &tile[bufi][chunk * 512]);                       \
        }                                                                      \
    }

    STAGE(0, ksbase);
    float nc_cur = negC0[ksbase + col];
    __syncthreads();

    for (int kc = 0; kc < 64; kc++) {
        int buf = kc & 1;
        float nc_next = 0.f;
        if (kc < 63) {
            STAGE(buf ^ 1, ksbase + (kc + 1) * KROWS);
            nc_next = negC0[ksbase + (kc + 1) * KROWS + col];
        }

        f32x16 a0, a1;
#pragma unroll
        for (int g = 0; g < 16; g++) { a0[g] = nc_cur; a1[g] = 0.f; }

        const u16* trow = &tile[buf][col * 256];
#pragma unroll
        for (int ks = 0; ks < 8; ks++) {
            int g0 = ((2 * ks) * 2 + half) ^ (col & 7);
            int g1 = ((2 * ks + 1) * 2 + half) ^ (col & 7);
            const bf16x8 Bf0 = *(const bf16x8*)(trow + g0 * 8);
            const bf16x8 Bf1 = *(const bf16x8*)(trow + g1 * 8);
            a0 = MFMA32_BF16(Ah[2 * ks], Bf0, a0);
            a1 = MFMA32_BF16(Ah[2 * ks + 1], Bf1, a1);
        }

        u32 orv = ((u32)kc << 5) | (u32)col;   // 11-bit id within split
#pragma unroll
        for (int g = 0; g < 16; g++) {
            u32 kb = (f2u(a0[g] + a1[g]) & 0xFFFFF800u) | orv;
            key[g] = min(key[g], kb);
        }
        nc_cur = nc_next;
        __syncthreads();  // drains prefetch + guards buffers
    }
#undef STAGE

    // top-2 across the 32 lanes (cols) sharing each C row
#pragma unroll
    for (int g = 0; g < 16; g++) {
        u32 k1 = key[g], k2 = 0xffffffffu;
#pragma unroll
        for (int m = 1; m < 32; m <<= 1) {
            u32 o1 = (u32)__shfl_xor((int)k1, m, 64);
            u32 o2 = (u32)__shfl_xor((int)k2, m, 64);
            u32 mx = max(k1, o1);
            k1 = min(k1, o1);
            k2 = min(min(k2, o2), mx);
        }
        if (col == 0) {
            int row = (g & 3) + 8 * (g >> 2) + 4 * half;
            int n = n0 + row;
            int base = (n * KSPLIT + blockIdx.y) * 2;
            // full key: [31:13] approx-distance bits | [12:0] global code id
            pkey[base]     = (k1 & 0xFFFFE000u) | ((u32)ksbase + (k1 & 2047u));
            pkey[base + 1] = (k2 & 0xFFFFE000u) | ((u32)ksbase + (k2 & 2047u));
        }
    }
}

// ---------------------------------------------------------------------------
// K3: exact fp64 rescore. R19 structure (verified): one wave per row reads
// the 8 full keys (distance|id, cross-split comparable), extracts the 4
// smallest via repeated min-reduce (ids globally unique), fp64-rescores only
// those 4 codes. Gather: 16 lanes cover 256 B contiguous per instruction.
// Named cand regs + select chain (rule #20).
__global__ __launch_bounds__(256) void k_rescore(const float* __restrict__ xp,
                                                 const float* __restrict__ cbT,
                                                 const u32* __restrict__ pkey,
                                                 u32* __restrict__ idxv,
                                                 float* __restrict__ outIdx,
                                                 float* __restrict__ pmin) {
    int tid = threadIdx.x, wave = tid >> 6, lane = tid & 63;
    int n = blockIdx.x * 4 + wave;

    u32 key = (lane < 8) ? pkey[n * 8 + lane] : 0xffffffffu;

    u32 cand0, cand1, cand2, cand3;
#define EXTRACT(C)                                                             \
    {                                                                          \
        u32 kmin = key;                                                        \
        kmin = min(kmin, (u32)__shfl_xor((int)kmin, 1, 64));                   \
        kmin = min(kmin, (u32)__shfl_xor((int)kmin, 2, 64));                   \
        kmin = min(kmin, (u32)__shfl_xor((int)kmin, 4, 64));                   \
        C = (u32)__shfl((int)kmin, 0, 64);                                     \
        if (key == C) key = 0xffffffffu;                                       \
    }
    EXTRACT(cand0)
    EXTRACT(cand1)
    EXTRACT(cand2)
    EXTRACT(cand3)
#undef EXTRACT

    int g = lane >> 4, sl = lane & 15;
    u32 ck = (g == 0) ? cand0 : (g == 1) ? cand1 : (g == 2) ? cand2 : cand3;
    u32 kg = ck & 8191u;

    const float* cv = cbT + (size_t)kg * DD;
    const float* xb = xp + n * DD;
    double s = 0.0;
#pragma unroll
    for (int t = 0; t < 4; t++) {
        f32x4 cvv = *(const f32x4*)(cv + (t * 16 + sl) * 4);
        f32x4 xvv = *(const f32x4*)(xb + (t * 16 + sl) * 4);
#pragma unroll
        for (int q = 0; q < 4; q++) {
            double d = (double)xvv[q] - (double)cvv[q];
            s += d * d;
        }
    }
    // reduce within each 16-lane group
    s += __shfl_xor(s, 1, 64);
    s += __shfl_xor(s, 2, 64);
    s += __shfl_xor(s, 4, 64);
    s += __shfl_xor(s, 8, 64);

    // compare across the 4 groups
    double bestv = s;
    u32 besti = kg;
#pragma unroll
    for (int m = 16; m < 64; m <<= 1) {
        double ov = __shfl_xor(bestv, m, 64);
        u32 oi = (u32)__shfl_xor((int)besti, m, 64);
        if (ov < bestv || (ov == bestv && oi < besti)) { bestv = ov; besti = oi; }
    }
    if (lane == 0) {
        idxv[n] = besti;
        outIdx[n] = (float)besti;
        pmin[n] = (float)bestv;
    }
}

// ---------------------------------------------------------------------------
// K5 (k_final folded in): gather quantized (B,D,H,W) fp32 via LDS transpose
// tiles; block NN/32 reduces pmin -> outDiff. Coalesced cbT staging reads.
// Rewrites ALL of d_out chunk 0.
__global__ __launch_bounds__(256) void k_gather(const float* __restrict__ cbT,
                                                const u32* __restrict__ idxv,
                                                const float* __restrict__ pmin,
                                                float* __restrict__ out0,
                                                float* __restrict__ outDiff) {
    if (blockIdx.x == NN / 32) {
        // fused k_final: diff = sum(pmin)/(N*D), fp64. 256 threads x 64 vals.
        __shared__ double sm[4];
        int tid = threadIdx.x, lane = tid & 63, wv = tid >> 6;
        double s = 0.0;
#pragma unroll
        for (int i = 0; i < 64; i++) s += (double)pmin[i * 256 + tid];
#pragma unroll
        for (int m = 1; m < 64; m <<= 1) s += __shfl_xor(s, m, 64);
        if (lane == 0) sm[wv] = s;
        __syncthreads();
        if (tid == 0)
            outDiff[0] = (float)((sm[0] + sm[1] + sm[2] + sm[3]) * (1.0 / (double)OUT0));
        return;
    }

    __shared__ float tile[32 * 260];
    int tid = threadIdx.x;
    int n0 = blockIdx.x * 32;
    int b = n0 >> 10, hw0 = n0 & 1023;

    {
        int r = tid >> 3, seg = tid & 7;
        u32 k = idxv[n0 + r] & 8191u;
        const float* src = cbT + (size_t)k * DD;
        float* dst = tile + r * 260;
#pragma unroll
        for (int j = 0; j < 8; j++)
            *(f32x4*)(dst + (j * 8 + seg) * 4) = *(const f32x4*)(src + (j * 8 + seg) * 4);
    }
    __syncthreads();
    {
        int hw = tid & 31, dq = tid >> 5;
        const float* trow = tile + hw * 260;
        float* obase = out0 + ((size_t)b * DD) * HW + hw0 + hw;
#pragma unroll
        for (int dj = 0; dj < 32; dj++) {
            int d = dq * 32 + dj;
            obase[(size_t)d * HW] = trow[d];
        }
    }
}

// ---------------------------------------------------------------------------
extern "C" void kernel_launch(void* const* d_in, const int* in_sizes, int n_in,
                              void* d_out, int out_size, void* d_ws, size_t ws_size,
                              hipStream_t stream) {
    const float* x = nullptr; const float* Wm = nullptr;
    const float* bias = nullptr; const float* cb = nullptr;
    for (int i = 0; i < n_in; i++) {
        switch (in_sizes[i]) {
            case 4194304: x    = (const float*)d_in[i]; break;  // (16,256,32,32)
            case 65536:   Wm   = (const float*)d_in[i]; break;  // (256,256)
            case 256:     bias = (const float*)d_in[i]; break;  // (256,)
            case 2097152: cb   = (const float*)d_in[i]; break;  // (256,8192)
        }
    }

    // d_out is FP32: [quantized (4194304) | diff (1) | indices (16384)]
    float* out0    = (float*)d_out;
    float* outDiff = (float*)d_out + OUT0;
    float* outIdx  = (float*)d_out + OUT0 + 1;

    // Transient scratch inside d_out chunk 0 (16.78 MB; every byte rewritten
    // by k_gather before the harness reads):
    char* o = (char*)d_out;
    u16*   cbTh = (u16*)o;                       // [0, 4 MB)
    u32*   pkey = (u32*)(o + 4194304);           // [4 MB, 4.5 MB) — 512 KB
    u16*   wh   = (u16*)(o + 6291456);           // 128 KB
    u16*   wm   = (u16*)(o + 6422528);           // 128 KB
    u16*   wl   = (u16*)(o + 6553600);           // 128 KB
    u16*   xpH  = (u16*)(o + 6750208);           // 8 MB  (N,D) bf16 -> ends 14.75 MB

    // Workspace (~25.33 MB, footprint that passed in rounds 4-9):
    char* w = (char*)d_ws;
    float* cbT   = (float*)(w);                  // 8 MB  (K,D) fp32
    float* xp    = (float*)(w + 8388608);        // 16 MB (N,D) fp32
    float* negC0 = (float*)(w + 25165824);       // 32 KB
    u32*   idxv  = (u32*)(w + 25198592);         // 64 KB
    float* pmin  = (float*)(w + 25264128);       // 64 KB

    k_prep<<<2560, 256, 0, stream>>>(cb, Wm, cbT, cbTh, negC0, wh, wm, wl);
    k_proj<<<NN / 8, 256, 0, stream>>>(x, wh, wm, wl, bias, xp, xpH);
    k_dist<<<dim3(NN / 128, KSPLIT), 256, 0, stream>>>(xpH, cbTh, negC0, pkey);
    k_rescore<<<NN / 4, 256, 0, stream>>>(xp, cbT, pkey, idxv, outIdx, pmin);
    k_gather<<<NN / 32 + 1, 256, 0, stream>>>(cbT, idxv, pmin, out0, outDiff);
}